// Round 6
// baseline (73761.041 us; speedup 1.0000x reference)
//
#include <hip/hip_runtime.h>
#include <math.h>

#define NN 2048   // 2L
#define LL 1024   // L
#define NSWB 8    // blocked Jacobi sweeps
#define NROUNDS (NSWB * 63)
#define PITER 10  // power iterations for spectral radius
#define JTAU 1e-8f   // relative off^2 threshold (|apq|_rel < 1e-4 -> identity)
#define STREAK_FULL 2016   // 63 rounds x 32 pairs all-skip = one clean sweep

// gctl layout (ints, zeroed at launch): [0]=gconv [1]=streak [2..65]=clean[64]

typedef float vf4 __attribute__((ext_vector_type(4)));   // asm-friendly reg quad

// ---------------------------------------------------------------------------
__global__ void build_H(const float* __restrict__ hop,  const float* __restrict__ swm,
                        const float* __restrict__ dwm,  const float* __restrict__ hv,
                        const float* __restrict__ sv,   const float* __restrict__ dv,
                        const float* __restrict__ X,    const float* __restrict__ Y,
                        const int*   __restrict__ ivic, const float* __restrict__ sb,
                        const float* __restrict__ gg,   const float* __restrict__ fS,
                        const float* __restrict__ fd,   float* __restrict__ W)
{
    int idx = blockIdx.x * 256 + threadIdx.x;
    int r = idx >> 11, c = idx & (NN - 1);
    float hv0 = hv[0], hv1 = hv[1], sv0 = sv[0], dv0 = dv[0];
    float g0 = gg[0], fS0 = fS[0], fd0 = fd[0];

    float val = 0.f;
    #pragma unroll
    for (int t = 0; t < 2; ++t) {
        int rr = t ? c : r;
        int cc = t ? r : c;
        int e  = rr * NN + cc;
        float v = hv0 * hop[e] - hop[NN*NN + e] + hv1 * hop[2*NN*NN + e]
                + sv0 * swm[e] + dv0 * dwm[e];
        int i = rr & (LL - 1), j = cc & (LL - 1);
        float px = 0.f, py = 0.f;
        float s = sb[i * LL + j];
        int n0 = ivic[i*4+0], n1 = ivic[i*4+1], n2 = ivic[i*4+2], n3 = ivic[i*4+3];
        if (j == n1 || j == n3) px = (X[j] - X[i]) * s;
        if (j == n0 || j == n2) py = (Y[j] - Y[i]) * s;
        float P = px + py, Mm = px - py;
        bool rlo = rr < LL, clo = cc < LL;
        if (rlo && clo)        v += g0 * P;
        else if (!rlo && !clo) v -= g0 * P;
        else                   v += fS0 * P + fd0 * Mm;
        val += 0.5f * v;
    }
    W[idx] = val;
}

// --------------------- power iteration for spectral radius ------------------
__global__ void powv_init(float* v)
{
    int i = blockIdx.x * 256 + threadIdx.x;
    if (i < NN) {
        unsigned h = (unsigned)i * 2654435761u;
        h ^= h >> 13; h *= 2246822519u; h ^= h >> 16;
        v[i] = ((h >> 8) * (1.0f / 16777216.f)) - 0.5f;
    }
}

__global__ void matvec(const float* __restrict__ W, const float* __restrict__ vin,
                       float* __restrict__ vout, double* accslot)
{
    __shared__ float red[256];
    int row = blockIdx.x, tid = threadIdx.x;
    const float* wr = W + (size_t)row * NN;
    float s = 0.f;
    for (int j = tid; j < NN; j += 256) s += wr[j] * vin[j];
    red[tid] = s; __syncthreads();
    for (int off = 128; off; off >>= 1) { if (tid < off) red[tid] += red[tid + off]; __syncthreads(); }
    if (tid == 0) { float y = red[0]; vout[row] = y; atomicAdd(accslot, (double)y * (double)y); }
}

__global__ void add_shift(float* W, const double* acc)
{
    int i = blockIdx.x * 256 + threadIdx.x;
    if (i < NN) {
        double n1 = acc[8 + PITER - 1], n0 = acc[8 + PITER - 2];
        float rho = (float)sqrt(n1 / (n0 > 0.0 ? n0 : 1.0));
        W[(size_t)i * NN + i] += 1.45f * rho;
    }
}

// ------------------- blocked Jacobi: fused persistent kernel ----------------
__device__ __forceinline__ void pair_groups(int pair, int r, int& gp, int& gq)
{
    if (pair == 0) gp = 0;
    else { int t1 = pair - 1 + r; if (t1 >= 63) t1 -= 63; gp = 1 + t1; }
    int t2 = 62 - pair + r; if (t2 >= 63) t2 -= 63; gq = 1 + t2;
}

// Fence-free coherence discipline (proven in v3): all cross-block traffic in
// the Jacobi loop uses IF$-coherent accesses (sc0 sc1 / relaxed agent
// atomics); NO acquire/release fences -> no buffer_wbl2/inv (the ~50us cost
// per barrier in v2). Ordering is manual: s_waitcnt vmcnt(0) before each
// barrier arrival; readers run after the barrier.
__device__ __forceinline__ int  ald(const int* p)
{ return __hip_atomic_load(p, __ATOMIC_RELAXED, __HIP_MEMORY_SCOPE_AGENT); }
__device__ __forceinline__ void ast(int* p, int v)
{ __hip_atomic_store(p, v, __ATOMIC_RELAXED, __HIP_MEMORY_SCOPE_AGENT); }
__device__ __forceinline__ void afst(float* p, float v)
{ __hip_atomic_store(p, v, __ATOMIC_RELAXED, __HIP_MEMORY_SCOPE_AGENT); }
__device__ __forceinline__ void afadd(float* p, float v)
{ (void)__hip_atomic_fetch_add(p, v, __ATOMIC_RELAXED, __HIP_MEMORY_SCOPE_AGENT); }

// IF$-coherent 16B load/store (single-writer data; atomicity not required,
// only coherence + manual ordering). ext_vector_type maps to a VGPR quad.
__device__ __forceinline__ vf4 cld4(const float* p)
{ vf4 d; asm volatile("global_load_dwordx4 %0, %1, off sc0 sc1" : "=v"(d) : "v"(p)); return d; }
__device__ __forceinline__ void cst4(float* p, vf4 v)
{ asm volatile("global_store_dwordx4 %0, %1, off sc0 sc1" :: "v"(p), "v"(v) : "memory"); }
__device__ __forceinline__ void waitvm0()
{ asm volatile("s_waitcnt vmcnt(0)" ::: "memory"); __builtin_amdgcn_sched_barrier(0); }

// global tree barrier, fence-free. Words spaced 4KB apart; XCD-local
// sub-counters (bid&7 groups follow the round-robin dispatch).
__device__ __forceinline__ void gridbar(int* bars, int phase)
{
    __syncthreads();
    if (threadIdx.x == 0) {
        asm volatile("s_waitcnt vmcnt(0)" ::: "memory");
        int g = blockIdx.x & 7;
        int old = __hip_atomic_fetch_add(&bars[g * 1024], 1,
                      __ATOMIC_RELAXED, __HIP_MEMORY_SCOPE_AGENT);
        if (old == phase * 64 - 1) {                       // group leader
            int t = __hip_atomic_fetch_add(&bars[8 * 1024], 1,
                        __ATOMIC_RELAXED, __HIP_MEMORY_SCOPE_AGENT);
            if (t == phase * 8 - 1)                        // global last
                ast(&bars[9 * 1024], phase);
        }
        while (ald(&bars[9 * 1024]) < phase)
            __builtin_amdgcn_s_sleep(8);
        asm volatile("" ::: "memory");
    }
    __syncthreads();
}

// pair-local barrier (16 blocks), fence-free; counter-only, monotone.
__device__ __forceinline__ void pairbar(int* ctr, int tgt)
{
    __syncthreads();
    if (threadIdx.x == 0) {
        asm volatile("s_waitcnt vmcnt(0)" ::: "memory");
        __hip_atomic_fetch_add(ctr, 1, __ATOMIC_RELAXED, __HIP_MEMORY_SCOPE_AGENT);
        while (ald(ctr) < tgt)
            __builtin_amdgcn_s_sleep(2);
        asm volatile("" ::: "memory");
    }
    __syncthreads();
}

// One kernel for all NSWB*63 rounds, 512 blocks x 512 threads (2/CU by LDS).
// Per round, block (pair,chunk) = (bid>>4, bid&15):
//   A: zero next-round Sg slice; stage own 64x128 W tile (dwordx4 sc0sc1) ->
//      TT; partial Gram; global_atomic_add_f32 into Sg[rr&1][pair] (64x64).
//   [pair barrier] -> Sg complete.
//   B: every block reads Sg (16KB) and redundantly runs the 63-iter solve
//      (identical bits -> identical V on all 16 blocks). No Gpart, no Vbuf.
//   C: apply TT x V -> W tile (dwordx4 sc0sc1), TT reused from A.
//   [global barrier]; uniform convergence break on gctl[0].
// Sg is double-buffered by round parity: buf (rr+1)&1 is zeroed in round rr
// (its last readers were in round rr-1, separated by the end-of-round
// gridbar), buf rr&1 receives adds (zeroed during round rr-1).
__global__ __launch_bounds__(512, 4) void jac_fused(float* __restrict__ W,
                                                    float* __restrict__ Sg,
                                                    int* __restrict__ gctl,
                                                    int* __restrict__ bars,
                                                    int* __restrict__ pbars)
{
    __shared__ float TT[64][132];   // A/C: 64-col x 128-row W tile
    __shared__ float S[64][65];     // B: pair Gram
    __shared__ float Vs[64][64];    // B->C: V tile
    __shared__ float csC[32], csS[32];
    __shared__ int   pk[32], qk[32];
    __shared__ int   active;
    __shared__ int   nact[2];

    const int tid   = threadIdx.x;
    const int bid   = blockIdx.x;
    const int gpair = bid >> 4, chunk = bid & 15;
    const int r0    = chunk * 128;
    const bool ldr  = (chunk == 0 && tid == 0);   // single writer for gctl
    int gphase = 0, pphase = 0;

    for (int rr = 0; rr < NROUNDS; ++rr) {
        int r = rr; while (r >= 63) r -= 63;
        int gp, gq; pair_groups(gpair, r, gp, gq);
        int c1 = ald(&gctl[2 + gp]);
        int c2 = ald(&gctl[2 + gq]);
        bool hint = (c1 >= 63 && c2 >= 63);

        // zero next-round Sg slice (unconditional; separated from its last
        // readers by the previous end-of-round gridbar)
        {
            float* bufn = Sg + ((size_t)(((rr + 1) & 1) * 32 + gpair)) * 4096 + chunk * 256;
            if (tid < 256) afst(&bufn[tid], 0.f);
        }

        // ---------------- phase A: stage + gram + accumulate ----------------
        if (!hint) {
            // tile = 2048 float4s; 4 per thread
            {
                int q  = tid & 31, r4 = q << 2;
                int cA = tid >> 5;
                vf4 t0 = cld4(W + (size_t)(gp * 32 + cA     ) * NN + r0 + r4);
                vf4 t1 = cld4(W + (size_t)(gp * 32 + cA + 16) * NN + r0 + r4);
                vf4 t2 = cld4(W + (size_t)(gq * 32 + cA     ) * NN + r0 + r4);
                vf4 t3 = cld4(W + (size_t)(gq * 32 + cA + 16) * NN + r0 + r4);
                waitvm0();
                *(vf4*)&TT[cA     ][r4] = t0;
                *(vf4*)&TT[cA + 16][r4] = t1;
                *(vf4*)&TT[cA + 32][r4] = t2;
                *(vf4*)&TT[cA + 48][r4] = t3;
            }
            __syncthreads();
            int tr = tid & 15, tc = tid >> 4;
            float acc[4][2] = {};
            for (int r4 = 0; r4 < 128; r4 += 4) {
                float a[4][4], b[2][4];
                #pragma unroll
                for (int m = 0; m < 4; ++m) *(float4*)a[m] = *(const float4*)&TT[tr + 16*m][r4];
                #pragma unroll
                for (int n = 0; n < 2; ++n) *(float4*)b[n] = *(const float4*)&TT[tc + 32*n][r4];
                #pragma unroll
                for (int m = 0; m < 4; ++m)
                    #pragma unroll
                    for (int n = 0; n < 2; ++n)
                        #pragma unroll
                        for (int k = 0; k < 4; ++k)
                            acc[m][n] += a[m][k] * b[n][k];
            }
            float* bufc = Sg + ((size_t)((rr & 1) * 32 + gpair)) * 4096;
            #pragma unroll
            for (int m = 0; m < 4; ++m)
                #pragma unroll
                for (int n = 0; n < 2; ++n)
                    afadd(&bufc[(tr + 16*m) * 64 + (tc + 32*n)], acc[m][n]);
        }
        pairbar(&pbars[gpair * 1024], 16 * (++pphase));

        // ---------------- phase B: redundant solve ----------------
        int do_apply = 0;
        if (hint) {
            if (ldr) {
                ast(&gctl[2 + gp], c1 + 1);
                ast(&gctl[2 + gq], c2 + 1);
                int old = __hip_atomic_fetch_add(&gctl[1], 1,
                              __ATOMIC_RELAXED, __HIP_MEMORY_SCOPE_AGENT);
                if (old + 1 >= STREAK_FULL) ast(&gctl[0], 1);
            }
        } else {
            if (tid == 0) active = 0;
            if (tid < 2) nact[tid] = 0;
            {
                const float* bufc = Sg + ((size_t)((rr & 1) * 32 + gpair)) * 4096;
                vf4 s0 = cld4(bufc + 4 * tid);
                vf4 s1 = cld4(bufc + 4 * (tid + 512));
                waitvm0();
                int i0 = tid >> 4,         j0 = (tid & 15) << 2;
                int i1 = (tid + 512) >> 4;
                S[i0][j0] = s0.x; S[i0][j0+1] = s0.y; S[i0][j0+2] = s0.z; S[i0][j0+3] = s0.w;
                S[i1][j0] = s1.x; S[i1][j0+1] = s1.y; S[i1][j0+2] = s1.z; S[i1][j0+3] = s1.w;
            }
            __syncthreads();
            int loc = 0;
            for (int e = tid; e < 4096; e += 512) {
                int i = e >> 6, j = e & 63;
                if (i < j) {
                    float o = S[i][j];
                    if (o * o > JTAU * S[i][i] * S[j][j]) loc = 1;
                }
            }
            if (loc) active = 1;          // benign race: only ever set to 1
            __syncthreads();
            if (!active) {
                if (ldr) {
                    ast(&gctl[2 + gp], c1 + 1);
                    ast(&gctl[2 + gq], c2 + 1);
                    int old = __hip_atomic_fetch_add(&gctl[1], 1,
                                  __ATOMIC_RELAXED, __HIP_MEMORY_SCOPE_AGENT);
                    if (old + 1 >= STREAK_FULL) ast(&gctl[0], 1);
                }
            } else {
                do_apply = 1;
                if (ldr) {
                    ast(&gctl[2 + gp], 0);
                    ast(&gctl[2 + gq], 0);
                    __hip_atomic_exchange(&gctl[1], 0,
                        __ATOMIC_RELAXED, __HIP_MEMORY_SCOPE_AGENT);
                }
                int lane = tid & 63, wv = tid >> 6;   // 8 waves; wave w owns V rows 8w..8w+7
                float v[8];
                #pragma unroll
                for (int i = 0; i < 8; ++i) v[i] = (8 * wv + i == lane) ? 1.f : 0.f;

                for (int r2 = 0; r2 < 63; ++r2) {
                    if (tid < 32) {
                        int k = tid, p, q;
                        if (k == 0) p = 0;
                        else { int t1 = k - 1 + r2; if (t1 >= 63) t1 -= 63; p = 1 + t1; }
                        int t2 = 62 - k + r2; if (t2 >= 63) t2 -= 63; q = 1 + t2;
                        float app = S[p][p], aqq = S[q][q], apq = S[p][q];
                        float c = 1.f, s = 0.f;
                        if (apq * apq > JTAU * app * aqq) {
                            // fast-math chain (~1e-7 rel; Jacobi self-corrects)
                            float tau = (aqq - app) * __builtin_amdgcn_rcpf(2.f * apq);
                            float sq  = __builtin_amdgcn_sqrtf(fmaf(tau, tau, 1.f));
                            float t   = (tau >= 0.f ? 1.f : -1.f) *
                                        __builtin_amdgcn_rcpf(fabsf(tau) + sq);
                            c = __builtin_amdgcn_rsqf(fmaf(t, t, 1.f));
                            s = t * c;
                            nact[r2 & 1] = 1;     // benign multi-writer, same value
                        }
                        csC[k] = c; csS[k] = s; pk[k] = p; qk[k] = q;
                    }
                    if (tid == 256) nact[(r2 + 1) & 1] = 0;
                    __syncthreads();
                    if (!nact[r2 & 1]) break;
                    // one-pass S <- J^T S J over disjoint 2x2 blocks (2/thread)
                    for (int u = tid; u < 1024; u += 512) {
                        int ki = u >> 5, kj = u & 31;
                        float si_ = csS[ki], sj_ = csS[kj];
                        if (si_ == 0.f && sj_ == 0.f) continue;
                        float ci_ = csC[ki], cj_ = csC[kj];
                        int pi = pk[ki], qi = qk[ki], pj = pk[kj], qj = qk[kj];
                        float a  = S[pi][pj], b  = S[pi][qj];
                        float c2 = S[qi][pj], d  = S[qi][qj];
                        float a1 = cj_ * a  - sj_ * b,  b1 = sj_ * a  + cj_ * b;
                        float c1 = cj_ * c2 - sj_ * d,  d1 = sj_ * c2 + cj_ * d;
                        S[pi][pj] = ci_ * a1 - si_ * c1;
                        S[qi][pj] = si_ * a1 + ci_ * c1;
                        S[pi][qj] = ci_ * b1 - si_ * d1;
                        S[qi][qj] = si_ * b1 + ci_ * d1;
                    }
                    // V <- V * J (register resident: lane = column, shfl p<->q)
                    {
                        int k;
                        if (lane == 0) k = 0;
                        else { int t = lane - 1 - r2; if (t < 0) t += 63;
                               k = (t <= 30) ? (t + 1) : (62 - t); }
                        float s_ = csS[k];
                        if (s_ != 0.f) {
                            float c_ = csC[k];
                            int p = pk[k], q = qk[k];
                            bool isp = (lane == p);
                            int part = isp ? q : p;
                            #pragma unroll
                            for (int i = 0; i < 8; ++i) {
                                float other = __shfl(v[i], part);
                                v[i] = isp ? (c_ * v[i] - s_ * other)
                                           : (s_ * other + c_ * v[i]);
                            }
                        }
                    }
                    __syncthreads();
                }
                #pragma unroll
                for (int i = 0; i < 8; ++i) Vs[8 * wv + i][lane] = v[i];
                __syncthreads();
            }
        }

        // ---------------- phase C: apply (TT from A, Vs from B) -------------
        if (do_apply) {
            int rt = tid & 31, ct = tid >> 5;
            int rr0 = rt << 2, c20 = ct << 2;
            float acc[4][4] = {};
            for (int c = 0; c < 64; ++c) {
                float a[4], b[4];
                *(float4*)a = *(const float4*)&TT[c][rr0];
                *(float4*)b = *(const float4*)&Vs[c][c20];
                #pragma unroll
                for (int i = 0; i < 4; ++i)
                    #pragma unroll
                    for (int j = 0; j < 4; ++j)
                        acc[i][j] += a[i] * b[j];
            }
            __syncthreads();           // everyone done reading TT
            #pragma unroll
            for (int j = 0; j < 4; ++j)
                #pragma unroll
                for (int i = 0; i < 4; ++i)
                    TT[c20 + j][rr0 + i] = acc[i][j];
            __syncthreads();
            {
                int q  = tid & 31, r4 = q << 2;
                int cA = tid >> 5;
                cst4(W + (size_t)(gp * 32 + cA     ) * NN + r0 + r4, *(const vf4*)&TT[cA     ][r4]);
                cst4(W + (size_t)(gp * 32 + cA + 16) * NN + r0 + r4, *(const vf4*)&TT[cA + 16][r4]);
                cst4(W + (size_t)(gq * 32 + cA     ) * NN + r0 + r4, *(const vf4*)&TT[cA + 32][r4]);
                cst4(W + (size_t)(gq * 32 + cA + 16) * NN + r0 + r4, *(const vf4*)&TT[cA + 48][r4]);
            }
        }
        gridbar(bars, ++gphase);
        if (ald(&gctl[0])) break;
    }
}

// --------------------- norms, selection, gather -----------------------------
__global__ void colnorms(const float* __restrict__ W, float* __restrict__ sig2)
{
    __shared__ float red[256];
    int col = blockIdx.x, tid = threadIdx.x;
    const float* c = W + (size_t)col * NN;
    float s = 0.f;
    for (int e = tid; e < NN; e += 256) s += c[e] * c[e];
    red[tid] = s; __syncthreads();
    for (int off = 128; off; off >>= 1) { if (tid < off) red[tid] += red[tid + off]; __syncthreads(); }
    if (tid == 0) sig2[col] = red[0];
}

__global__ void select_k(const float* __restrict__ sig2, int* __restrict__ sel)
{
    int i = blockIdx.x * 256 + threadIdx.x;
    if (i >= NN) return;
    float di = sig2[i]; int rank = 0;
    for (int j = 0; j < NN; ++j) {
        float dj = sig2[j];
        rank += (dj < di) || (dj == di && j < i);
    }
    if (rank < LL) sel[rank] = i;
}

__global__ void gather_M(const float* __restrict__ W, const float* __restrict__ sig2,
                         const int* __restrict__ sel, const int* __restrict__ occ,
                         float* __restrict__ Mt)
{
    int idx = blockIdx.x * 256 + threadIdx.x;
    int b = idx >> 10, a = idx & (LL - 1);
    int col = sel[b];
    float rn = 1.f / sqrtf(sig2[col]);
    Mt[(size_t)b * LL + a] = W[(size_t)col * NN + occ[a]] * rn;
}

// G = Mt^T * Mt in fp64 (= M M^T)
__global__ void gram(const float* __restrict__ Mt, double* __restrict__ G)
{
    __shared__ float As[32][17], Bs[32][17];
    int t = threadIdx.x;
    int tx = t & 15, ty = t >> 4;
    int a0 = blockIdx.y * 16, c0 = blockIdx.x * 16;
    double s = 0.0;
    for (int kb = 0; kb < LL; kb += 32) {
        for (int u = t; u < 32 * 16; u += 256) {
            int kr = u >> 4, i = u & 15;
            As[kr][i] = Mt[(size_t)(kb + kr) * LL + a0 + i];
            Bs[kr][i] = Mt[(size_t)(kb + kr) * LL + c0 + i];
        }
        __syncthreads();
        #pragma unroll 8
        for (int k2 = 0; k2 < 32; ++k2)
            s += (double)As[k2][ty] * (double)Bs[k2][tx];
        __syncthreads();
    }
    G[(size_t)(a0 + ty) * LL + (c0 + tx)] = s;
}

// --------------------- blocked fp64 Cholesky (panel 64) ---------------------
__global__ void chol_panel(double* __restrict__ G, int k0, double* __restrict__ acc)
{
    __shared__ double Ld[64][65];
    __shared__ double sinv;
    int tid = threadIdx.x;
    for (int u = tid; u < 4096; u += 256)
        Ld[u >> 6][u & 63] = G[(size_t)(k0 + (u >> 6)) * LL + k0 + (u & 63)];
    __syncthreads();
    double lsum = 0.0;
    for (int c = 0; c < 64; ++c) {
        if (tid == 0) {
            double d = Ld[c][c]; d = d > 1e-300 ? d : 1e-300;
            double sd = sqrt(d); lsum += log(sd);
            Ld[c][c] = sd; sinv = 1.0 / sd;
        }
        __syncthreads();
        if (tid < 63 - c) Ld[c + 1 + tid][c] *= sinv;
        __syncthreads();
        for (int u = tid; u < 4096; u += 256) {
            int rr = u >> 6, cc = u & 63;
            if (rr > c && cc > c) Ld[rr][cc] -= Ld[rr][c] * Ld[cc][c];
        }
        __syncthreads();
    }
    for (int u = tid; u < 4096; u += 256)
        G[(size_t)(k0 + (u >> 6)) * LL + k0 + (u & 63)] = Ld[u >> 6][u & 63];
    if (tid == 0) atomicAdd(acc + 1, lsum);
}

__global__ void chol_trsm(double* __restrict__ G, int k0)
{
    __shared__ double L11[64][65];
    __shared__ double Rt[32][65];
    int tid = threadIdx.x;
    int rbase = k0 + 64 + blockIdx.x * 32;
    for (int u = tid; u < 4096; u += 256)
        L11[u >> 6][u & 63] = G[(size_t)(k0 + (u >> 6)) * LL + k0 + (u & 63)];
    for (int u = tid; u < 2048; u += 256)
        Rt[u >> 6][u & 63] = G[(size_t)(rbase + (u >> 6)) * LL + k0 + (u & 63)];
    __syncthreads();
    for (int c = 0; c < 64; ++c) {
        if (tid < 32) Rt[tid][c] *= 1.0 / L11[c][c];
        __syncthreads();
        for (int u = tid; u < 2048; u += 256) {
            int rr = u >> 6, cc = u & 63;
            if (cc > c) Rt[rr][cc] -= Rt[rr][c] * L11[cc][c];
        }
        __syncthreads();
    }
    for (int u = tid; u < 2048; u += 256)
        G[(size_t)(rbase + (u >> 6)) * LL + k0 + (u & 63)] = Rt[u >> 6][u & 63];
}

__global__ void chol_syrk(double* __restrict__ G, int k0)
{
    __shared__ double At[64][32];
    __shared__ double Bt[64][32];
    int tid = threadIdx.x;
    int r0g = k0 + 64 + blockIdx.y * 64;
    int c0g = k0 + 64 + blockIdx.x * 64;
    int i0 = (tid >> 4) << 2, j0 = (tid & 15) << 2;
    double acc[4][4] = {};
    for (int kh = 0; kh < 2; ++kh) {
        for (int u = tid; u < 2048; u += 256) {
            int i = u >> 5, c = u & 31;
            At[i][c] = G[(size_t)(r0g + i) * LL + k0 + kh * 32 + c];
            Bt[i][c] = G[(size_t)(c0g + i) * LL + k0 + kh * 32 + c];
        }
        __syncthreads();
        for (int c = 0; c < 32; ++c) {
            int cr = (c + tid) & 31;
            double a[4], b[4];
            #pragma unroll
            for (int i = 0; i < 4; ++i) a[i] = At[i0 + i][cr];
            #pragma unroll
            for (int j = 0; j < 4; ++j) b[j] = Bt[j0 + j][cr];
            #pragma unroll
            for (int i = 0; i < 4; ++i)
                #pragma unroll
                for (int j = 0; j < 4; ++j)
                    acc[i][j] += a[i] * b[j];
        }
        __syncthreads();
    }
    #pragma unroll
    for (int i = 0; i < 4; ++i)
        #pragma unroll
        for (int j = 0; j < 4; ++j) {
            size_t e = (size_t)(r0g + i0 + i) * LL + c0g + j0 + j;
            G[e] -= acc[i][j];
        }
}

// --------- all O(L^2) circulant quadratic forms + coherent terms ------------
__global__ void pair_sums(const float* __restrict__ Sz,  const float* __restrict__ X,
                          const float* __restrict__ Y,
                          const float* __restrict__ Jsp, const float* __restrict__ JXel,
                          const float* __restrict__ JYel,const float* __restrict__ pXX,
                          const float* __restrict__ pXY, const float* __restrict__ pYY,
                          const float* __restrict__ sb,  const float* __restrict__ stx,
                          const float* __restrict__ sty,
                          const float* __restrict__ zx,  const float* __restrict__ zy,
                          const float* __restrict__ xr,  const float* __restrict__ yr,
                          double* __restrict__ acc)
{
    __shared__ float tS[289], tXe[289], tYe[289], tXX[289], tXY[289], tYY[289];
    __shared__ double red[256];
    int tid = threadIdx.x;
    for (int u = tid; u < 289; u += 256) {
        tS[u]  = (u < 288) ? Jsp[u] : 0.f;
        tXX[u] = (u < 288) ? pXX[u] : 0.f;
        tXY[u] = (u < 288) ? pXY[u] : 0.f;
        tYY[u] = (u < 288) ? pYY[u] : 0.f;
        tXe[u] = (u >= 1 && u < 288) ? JXel[u - 1] : 0.f;
        tYe[u] = (u >= 1 && u < 288) ? JYel[u - 1] : 0.f;
    }
    __syncthreads();
    int idx = blockIdx.x * 256 + tid;
    int i = idx >> 10, j = idx & (LL - 1);
    int xi = i >> 5, yi = i & 31, xj = j >> 5, yj = j & 31;
    int dx = (xj - xi) & 31, dy = (yj - yi) & 31;
    int rx = (dx <= 16) ? dx : 32 - dx;
    int ry = (dy <= 16) ? dy : 32 - dy;
    int ti = rx * 17 + ry;
    float si = Sz[i], sj = Sz[j];
    float Xi = X[i], Xj = X[j], Yi = Y[i], Yj = Y[j];
    float sbij = sb[i * LL + j];
    double sum = (double)(si * sj) * (double)tS[ti];
    sum += (double)(Xi * Xj) * (double)tXX[ti];
    sum += (double)(Yi * Xj + Xi * Yj) * (double)tXY[ti];
    sum += (double)(Yi * Yj) * (double)tYY[ti];
    sum += (double)(si * sj * sbij) *
           ((double)tXe[ti] * (double)(Xi - Xj) + (double)tYe[ti] * (double)(Yi - Yj));
    if (i == j) {
        float ex = Xi - zx[0] * stx[i];
        float ey = Yi - zy[0] * sty[i];
        sum -= 0.5 * (double)xr[0] * ex * ex + 0.5 * (double)yr[0] * ey * ey;
    }
    red[tid] = sum; __syncthreads();
    for (int off = 128; off; off >>= 1) { if (tid < off) red[tid] += red[tid + off]; __syncthreads(); }
    if (tid == 0) atomicAdd(&acc[0], red[0]);
}

__global__ void finalize(const double* __restrict__ acc, float* __restrict__ out)
{
    out[0] = (float)(acc[0] + acc[1]);
}

// ---------------------------------------------------------------------------
extern "C" void kernel_launch(void* const* d_in, const int* in_sizes, int n_in,
                              void* d_out, int out_size, void* d_ws, size_t ws_size,
                              hipStream_t stream)
{
    const int*   occ  = (const int*)  d_in[0];
    const float* Sz   = (const float*)d_in[2];
    const float* X    = (const float*)d_in[3];
    const float* Y    = (const float*)d_in[4];
    const float* hv   = (const float*)d_in[5];
    const float* sv   = (const float*)d_in[6];
    const float* dv   = (const float*)d_in[7];
    const float* Jsp  = (const float*)d_in[8];
    const float* JXel = (const float*)d_in[9];
    const float* JYel = (const float*)d_in[10];
    const float* pXX  = (const float*)d_in[11];
    const float* pXY  = (const float*)d_in[12];
    const float* pYY  = (const float*)d_in[13];
    const float* g    = (const float*)d_in[14];
    const float* fS   = (const float*)d_in[15];
    const float* fd   = (const float*)d_in[16];
    const float* zx   = (const float*)d_in[17];
    const float* zy   = (const float*)d_in[18];
    const float* xr   = (const float*)d_in[19];
    const float* yr   = (const float*)d_in[20];
    const float* hop  = (const float*)d_in[21];
    const float* swm  = (const float*)d_in[22];
    const float* dwm  = (const float*)d_in[23];
    const int*   ivic = (const int*)  d_in[24];
    const float* sb   = (const float*)d_in[25];
    const float* stx  = (const float*)d_in[26];
    const float* sty  = (const float*)d_in[27];
    float* out = (float*)d_out;

    char* ws = (char*)d_ws;
    float*  W    = (float*) (ws + 0);           // 16.78 MB
    float*  v0   = (float*) (ws + 16777216);    // 8 KB
    float*  v1   = (float*) (ws + 16785408);    // 4 KB used
    float*  sig2 = (float*) (ws + 16793600);
    int*    sel  = (int*)   (ws + 16801792);
    float*  Mt   = (float*) (ws + 16805888);    // 4 MB; first 172KB doubles as barrier words during Jacobi
    double* G    = (double*)(ws + 21000192);    // 8 MB fp64 Gram; first 1MB doubles as Sg (fp32) during Jacobi
    double* acc  = (double*)(ws + 29388800);    // 32 doubles
    int*    gctl = (int*)   (ws + 29389056);    // [0]=gconv [1]=streak [2..65]=clean
    int*    bars  = (int*)  Mt;                 // global barrier: 10 x 4KB-spaced words
    int*    pbars = bars + 10 * 1024;           // pair barriers: 32 x 4KB-spaced words
    float*  Sg    = (float*)G;                  // 2 x 32 x 4096 floats, double-buffered

    (void)hipMemsetAsync(acc, 0, 768, stream);              // acc + gctl
    (void)hipMemsetAsync(bars, 0, 42 * 4096, stream);       // barrier words
    (void)hipMemsetAsync(Sg, 0, 2 * 32 * 4096 * 4, stream); // Sg both parity buffers
    build_H<<<NN * NN / 256, 256, 0, stream>>>(hop, swm, dwm, hv, sv, dv, X, Y,
                                               ivic, sb, g, fS, fd, W);
    powv_init<<<8, 256, 0, stream>>>(v0);
    for (int it = 0; it < PITER; ++it) {
        const float* vin = (it & 1) ? v1 : v0;
        float* vout = (it & 1) ? v0 : v1;
        matvec<<<NN, 256, 0, stream>>>(W, vin, vout, acc + 8 + it);
    }
    add_shift<<<8, 256, 0, stream>>>(W, acc);

    // single persistent kernel for all NSWB*63 Jacobi rounds
    jac_fused<<<512, 512, 0, stream>>>(W, Sg, gctl, bars, pbars);

    colnorms<<<NN, 256, 0, stream>>>(W, sig2);
    select_k<<<8, 256, 0, stream>>>(sig2, sel);
    gather_M<<<4096, 256, 0, stream>>>(W, sig2, sel, occ, Mt);
    gram<<<dim3(64, 64), 256, 0, stream>>>(Mt, G);

    for (int s = 0; s < 16; ++s) {
        int k0 = s * 64;
        chol_panel<<<1, 256, 0, stream>>>(G, k0, acc);
        int nrows = LL - k0 - 64;
        if (nrows > 0) {
            chol_trsm<<<nrows / 32, 256, 0, stream>>>(G, k0);
            chol_syrk<<<dim3(nrows / 64, nrows / 64), 256, 0, stream>>>(G, k0);
        }
    }

    pair_sums<<<4096, 256, 0, stream>>>(Sz, X, Y, Jsp, JXel, JYel, pXX, pXY, pYY,
                                        sb, stx, sty, zx, zy, xr, yr, acc);
    finalize<<<1, 1, 0, stream>>>(acc, out);
}

// Round 8
// 63908.295 us; speedup vs baseline: 1.1542x; 1.1542x over previous
//
#include <hip/hip_runtime.h>
#include <math.h>

#define NN 2048   // 2L
#define LL 1024   // L
#define NSWB 8    // blocked Jacobi sweeps
#define NROUNDS (NSWB * 63)
#define PITER 10  // power iterations for spectral radius
#define JTAU 1e-8f   // relative off^2 threshold (|apq|_rel < 1e-4 -> identity)
#define STREAK_FULL 2016   // 63 rounds x 32 pairs all-skip = one clean sweep

// gctl layout (ints, zeroed at launch): [0]=gconv [1]=streak [2..65]=clean[64]

typedef float vf4 __attribute__((ext_vector_type(4)));   // asm-friendly reg quad

// ---------------------------------------------------------------------------
__global__ void build_H(const float* __restrict__ hop,  const float* __restrict__ swm,
                        const float* __restrict__ dwm,  const float* __restrict__ hv,
                        const float* __restrict__ sv,   const float* __restrict__ dv,
                        const float* __restrict__ X,    const float* __restrict__ Y,
                        const int*   __restrict__ ivic, const float* __restrict__ sb,
                        const float* __restrict__ gg,   const float* __restrict__ fS,
                        const float* __restrict__ fd,   float* __restrict__ W)
{
    int idx = blockIdx.x * 256 + threadIdx.x;
    int r = idx >> 11, c = idx & (NN - 1);
    float hv0 = hv[0], hv1 = hv[1], sv0 = sv[0], dv0 = dv[0];
    float g0 = gg[0], fS0 = fS[0], fd0 = fd[0];

    float val = 0.f;
    #pragma unroll
    for (int t = 0; t < 2; ++t) {
        int rr = t ? c : r;
        int cc = t ? r : c;
        int e  = rr * NN + cc;
        float v = hv0 * hop[e] - hop[NN*NN + e] + hv1 * hop[2*NN*NN + e]
                + sv0 * swm[e] + dv0 * dwm[e];
        int i = rr & (LL - 1), j = cc & (LL - 1);
        float px = 0.f, py = 0.f;
        float s = sb[i * LL + j];
        int n0 = ivic[i*4+0], n1 = ivic[i*4+1], n2 = ivic[i*4+2], n3 = ivic[i*4+3];
        if (j == n1 || j == n3) px = (X[j] - X[i]) * s;
        if (j == n0 || j == n2) py = (Y[j] - Y[i]) * s;
        float P = px + py, Mm = px - py;
        bool rlo = rr < LL, clo = cc < LL;
        if (rlo && clo)        v += g0 * P;
        else if (!rlo && !clo) v -= g0 * P;
        else                   v += fS0 * P + fd0 * Mm;
        val += 0.5f * v;
    }
    W[idx] = val;
}

// --------------------- power iteration for spectral radius ------------------
__global__ void powv_init(float* v)
{
    int i = blockIdx.x * 256 + threadIdx.x;
    if (i < NN) {
        unsigned h = (unsigned)i * 2654435761u;
        h ^= h >> 13; h *= 2246822519u; h ^= h >> 16;
        v[i] = ((h >> 8) * (1.0f / 16777216.f)) - 0.5f;
    }
}

__global__ void matvec(const float* __restrict__ W, const float* __restrict__ vin,
                       float* __restrict__ vout, double* accslot)
{
    __shared__ float red[256];
    int row = blockIdx.x, tid = threadIdx.x;
    const float* wr = W + (size_t)row * NN;
    float s = 0.f;
    for (int j = tid; j < NN; j += 256) s += wr[j] * vin[j];
    red[tid] = s; __syncthreads();
    for (int off = 128; off; off >>= 1) { if (tid < off) red[tid] += red[tid + off]; __syncthreads(); }
    if (tid == 0) { float y = red[0]; vout[row] = y; atomicAdd(accslot, (double)y * (double)y); }
}

__global__ void add_shift(float* W, const double* acc)
{
    int i = blockIdx.x * 256 + threadIdx.x;
    if (i < NN) {
        double n1 = acc[8 + PITER - 1], n0 = acc[8 + PITER - 2];
        float rho = (float)sqrt(n1 / (n0 > 0.0 ? n0 : 1.0));
        W[(size_t)i * NN + i] += 1.45f * rho;
    }
}

// ------------------- blocked Jacobi: fused persistent kernel ----------------
__device__ __forceinline__ void pair_groups(int pair, int r, int& gp, int& gq)
{
    if (pair == 0) gp = 0;
    else { int t1 = pair - 1 + r; if (t1 >= 63) t1 -= 63; gp = 1 + t1; }
    int t2 = 62 - pair + r; if (t2 >= 63) t2 -= 63; gq = 1 + t2;
}

// Fence-free coherence discipline (proven in v3/v5): all cross-block traffic
// uses IF$-coherent accesses (sc0 sc1 / relaxed agent atomics); NO
// acquire/release fences -> no buffer_wbl2/inv. Ordering is manual: every
// wave drains vmcnt(0) before its block's barrier arrival / flag publish.
__device__ __forceinline__ int  ald(const int* p)
{ return __hip_atomic_load(p, __ATOMIC_RELAXED, __HIP_MEMORY_SCOPE_AGENT); }
__device__ __forceinline__ void ast(int* p, int v)
{ __hip_atomic_store(p, v, __ATOMIC_RELAXED, __HIP_MEMORY_SCOPE_AGENT); }
__device__ __forceinline__ void afst(float* p, float v)
{ __hip_atomic_store(p, v, __ATOMIC_RELAXED, __HIP_MEMORY_SCOPE_AGENT); }
__device__ __forceinline__ void afadd(float* p, float v)
{ (void)__hip_atomic_fetch_add(p, v, __ATOMIC_RELAXED, __HIP_MEMORY_SCOPE_AGENT); }

// IF$-coherent load/store (single-writer data; atomicity not required,
// only coherence + manual ordering). ext_vector_type maps to a VGPR quad.
__device__ __forceinline__ vf4 cld4(const float* p)
{ vf4 d; asm volatile("global_load_dwordx4 %0, %1, off sc0 sc1" : "=v"(d) : "v"(p)); return d; }
__device__ __forceinline__ void cst4(float* p, vf4 v)
{ asm volatile("global_store_dwordx4 %0, %1, off sc0 sc1" :: "v"(p), "v"(v) : "memory"); }
__device__ __forceinline__ void cst1(float* p, float v)
{ asm volatile("global_store_dword %0, %1, off sc0 sc1" :: "v"(p), "v"(v) : "memory"); }
__device__ __forceinline__ void waitvm0()
{ asm volatile("s_waitcnt vmcnt(0)" ::: "memory"); __builtin_amdgcn_sched_barrier(0); }

// global tree barrier, fence-free. Words spaced 4KB apart; XCD-local
// sub-counters. ALL waves drain vmcnt before arrival.
__device__ __forceinline__ void gridbar(int* bars, int phase)
{
    waitvm0();
    __syncthreads();
    if (threadIdx.x == 0) {
        int g = blockIdx.x & 7;
        int old = __hip_atomic_fetch_add(&bars[g * 1024], 1,
                      __ATOMIC_RELAXED, __HIP_MEMORY_SCOPE_AGENT);
        if (old == phase * 64 - 1) {                       // group leader
            int t = __hip_atomic_fetch_add(&bars[8 * 1024], 1,
                        __ATOMIC_RELAXED, __HIP_MEMORY_SCOPE_AGENT);
            if (t == phase * 8 - 1)                        // global last
                ast(&bars[9 * 1024], phase);
        }
        while (ald(&bars[9 * 1024]) < phase)
            __builtin_amdgcn_s_sleep(8);
        asm volatile("" ::: "memory");
    }
    __syncthreads();
}

// One kernel for all NSWB*63 rounds, 512 blocks x 512 threads (2/CU by LDS).
// Per round, block (pair,chunk) = (bid>>4, bid&15); solver chunk = pair>>1
// (guarantees no two solver blocks co-reside on one CU under round-robin
// dispatch: co-residents are (b, b+256), and solver ids 16p+(p>>1) vs
// 16(p+16)+((p+16)>>1) differ by 264, never 256).
//   A: zero next-round Sg slice; stage own 64x128 W tile -> TT; partial
//      Gram; global_atomic_add_f32 into Sg[rr&1][pair]; arrive at pbars.
//   B: SOLVER spins for 16 arrivals, reduces Sg -> S, runs the 63-iter
//      solve (V in registers), writes Vbuf + publishes vstat = pphase*2+act.
//      NON-SOLVERS poll vstat, then read Vbuf -> Vs. No redundant solve ->
//      one solver per CU, private LDS pipe.
//   C: apply TT x V -> W tile (TT reused from A).
//   [global barrier]; uniform convergence break on gctl[0].
// hint is pair-uniform: gctl group words are written only by the owning
// pair's solver in phase B (vmcnt-drained before the end-of-round gridbar)
// and read at round start after the gridbar -> all 16 chunks agree, so
// pphase stays lockstep across the pair (no protocol divergence).
__global__ __launch_bounds__(512, 4) void jac_fused(float* __restrict__ W,
                                                    float* __restrict__ Sg,
                                                    float* __restrict__ Vbuf,
                                                    int* __restrict__ gctl,
                                                    int* __restrict__ bars,
                                                    int* __restrict__ pbars,
                                                    int* __restrict__ vstat)
{
    __shared__ float TT[64][132];   // A/C: 64-col x 128-row W tile
    __shared__ float S[64][65];     // B(solver): pair Gram
    __shared__ float Vs[64][64];    // B->C: V tile
    __shared__ float csC[32], csS[32];
    __shared__ int   pk[32], qk[32];
    __shared__ int   active;
    __shared__ int   nact[2];

    const int tid    = threadIdx.x;
    const int bid    = blockIdx.x;
    const int gpair  = bid >> 4, chunk = bid & 15;
    const int r0     = chunk * 128;
    const bool issol = (chunk == (gpair >> 1));
    const bool ldr   = (issol && tid == 0);      // single writer for gctl
    int gphase = 0, pphase = 0;

    for (int rr = 0; rr < NROUNDS; ++rr) {
        int r = rr; while (r >= 63) r -= 63;
        int gp, gq; pair_groups(gpair, r, gp, gq);
        int c1 = ald(&gctl[2 + gp]);
        int c2 = ald(&gctl[2 + gq]);
        bool hint = (c1 >= 63 && c2 >= 63);
        if (!hint) ++pphase;                     // consistent across the pair

        // zero next-round Sg slice (last readers were last round, separated
        // by the end-of-round gridbar)
        {
            float* bufn = Sg + ((size_t)(((rr + 1) & 1) * 32 + gpair)) * 4096 + chunk * 256;
            if (tid < 256) afst(&bufn[tid], 0.f);
        }

        // ---------------- phase A: stage + gram + accumulate ----------------
        if (!hint) {
            {
                int q  = tid & 31, r4 = q << 2;
                int cA = tid >> 5;
                vf4 t0 = cld4(W + (size_t)(gp * 32 + cA     ) * NN + r0 + r4);
                vf4 t1 = cld4(W + (size_t)(gp * 32 + cA + 16) * NN + r0 + r4);
                vf4 t2 = cld4(W + (size_t)(gq * 32 + cA     ) * NN + r0 + r4);
                vf4 t3 = cld4(W + (size_t)(gq * 32 + cA + 16) * NN + r0 + r4);
                waitvm0();
                *(vf4*)&TT[cA     ][r4] = t0;
                *(vf4*)&TT[cA + 16][r4] = t1;
                *(vf4*)&TT[cA + 32][r4] = t2;
                *(vf4*)&TT[cA + 48][r4] = t3;
            }
            __syncthreads();
            int tr = tid & 15, tc = tid >> 4;
            float acc[4][2] = {};
            for (int r4 = 0; r4 < 128; r4 += 4) {
                float a[4][4], b[2][4];
                #pragma unroll
                for (int m = 0; m < 4; ++m) *(float4*)a[m] = *(const float4*)&TT[tr + 16*m][r4];
                #pragma unroll
                for (int n = 0; n < 2; ++n) *(float4*)b[n] = *(const float4*)&TT[tc + 32*n][r4];
                #pragma unroll
                for (int m = 0; m < 4; ++m)
                    #pragma unroll
                    for (int n = 0; n < 2; ++n)
                        #pragma unroll
                        for (int k = 0; k < 4; ++k)
                            acc[m][n] += a[m][k] * b[n][k];
            }
            float* bufc = Sg + ((size_t)((rr & 1) * 32 + gpair)) * 4096;
            #pragma unroll
            for (int m = 0; m < 4; ++m)
                #pragma unroll
                for (int n = 0; n < 2; ++n)
                    afadd(&bufc[(tr + 16*m) * 64 + (tc + 32*n)], acc[m][n]);
            waitvm0();                 // every wave drains its Sg adds
            __syncthreads();
            if (tid == 0)
                (void)__hip_atomic_fetch_add(&pbars[gpair * 1024], 1,
                          __ATOMIC_RELAXED, __HIP_MEMORY_SCOPE_AGENT);
        }

        // ---------------- phase B ----------------
        int do_apply = 0;
        if (hint) {
            if (ldr) {
                ast(&gctl[2 + gp], c1 + 1);
                ast(&gctl[2 + gq], c2 + 1);
                int old = __hip_atomic_fetch_add(&gctl[1], 1,
                              __ATOMIC_RELAXED, __HIP_MEMORY_SCOPE_AGENT);
                if (old + 1 >= STREAK_FULL) ast(&gctl[0], 1);
            }
        } else if (issol) {
            // ---- solver: wait for all 16 Gram contributions ----
            if (tid == 0) {
                while (ald(&pbars[gpair * 1024]) < 16 * pphase)
                    __builtin_amdgcn_s_sleep(4);
                active = 0;
            }
            if (tid < 2) nact[tid] = 0;
            __syncthreads();
            {
                const float* bufc = Sg + ((size_t)((rr & 1) * 32 + gpair)) * 4096;
                vf4 s0 = cld4(bufc + 4 * tid);
                vf4 s1 = cld4(bufc + 4 * (tid + 512));
                waitvm0();
                int i0 = tid >> 4, j0 = (tid & 15) << 2;
                int i1 = (tid + 512) >> 4;
                S[i0][j0] = s0.x; S[i0][j0+1] = s0.y; S[i0][j0+2] = s0.z; S[i0][j0+3] = s0.w;
                S[i1][j0] = s1.x; S[i1][j0+1] = s1.y; S[i1][j0+2] = s1.z; S[i1][j0+3] = s1.w;
            }
            __syncthreads();
            int loc = 0;
            for (int e = tid; e < 4096; e += 512) {
                int i = e >> 6, j = e & 63;
                if (i < j) {
                    float o = S[i][j];
                    if (o * o > JTAU * S[i][i] * S[j][j]) loc = 1;
                }
            }
            if (loc) active = 1;          // benign race: only ever set to 1
            __syncthreads();
            if (!active) {
                if (tid == 0) {
                    ast(&gctl[2 + gp], c1 + 1);
                    ast(&gctl[2 + gq], c2 + 1);
                    int old = __hip_atomic_fetch_add(&gctl[1], 1,
                                  __ATOMIC_RELAXED, __HIP_MEMORY_SCOPE_AGENT);
                    if (old + 1 >= STREAK_FULL) ast(&gctl[0], 1);
                    ast(&vstat[gpair * 32], pphase * 2);     // publish: identity
                }
            } else {
                do_apply = 1;
                if (tid == 0) {
                    ast(&gctl[2 + gp], 0);
                    ast(&gctl[2 + gq], 0);
                    __hip_atomic_exchange(&gctl[1], 0,
                        __ATOMIC_RELAXED, __HIP_MEMORY_SCOPE_AGENT);
                }
                int lane = tid & 63, wv = tid >> 6;   // 8 waves; wave w owns V rows 8w..8w+7
                float v[8];
                #pragma unroll
                for (int i = 0; i < 8; ++i) v[i] = (8 * wv + i == lane) ? 1.f : 0.f;

                for (int r2 = 0; r2 < 63; ++r2) {
                    if (tid < 32) {
                        int k = tid, p, q;
                        if (k == 0) p = 0;
                        else { int t1 = k - 1 + r2; if (t1 >= 63) t1 -= 63; p = 1 + t1; }
                        int t2 = 62 - k + r2; if (t2 >= 63) t2 -= 63; q = 1 + t2;
                        float app = S[p][p], aqq = S[q][q], apq = S[p][q];
                        float c = 1.f, s = 0.f;
                        if (apq * apq > JTAU * app * aqq) {
                            // fast-math chain (~1e-7 rel; Jacobi self-corrects)
                            float tau = (aqq - app) * __builtin_amdgcn_rcpf(2.f * apq);
                            float sq  = __builtin_amdgcn_sqrtf(fmaf(tau, tau, 1.f));
                            float t   = (tau >= 0.f ? 1.f : -1.f) *
                                        __builtin_amdgcn_rcpf(fabsf(tau) + sq);
                            c = __builtin_amdgcn_rsqf(fmaf(t, t, 1.f));
                            s = t * c;
                            nact[r2 & 1] = 1;     // benign multi-writer, same value
                        }
                        csC[k] = c; csS[k] = s; pk[k] = p; qk[k] = q;
                    }
                    if (tid == 256) nact[(r2 + 1) & 1] = 0;
                    __syncthreads();
                    if (!nact[r2 & 1]) break;
                    // one-pass S <- J^T S J over disjoint 2x2 blocks (2/thread)
                    for (int u = tid; u < 1024; u += 512) {
                        int ki = u >> 5, kj = u & 31;
                        float si_ = csS[ki], sj_ = csS[kj];
                        if (si_ == 0.f && sj_ == 0.f) continue;
                        float ci_ = csC[ki], cj_ = csC[kj];
                        int pi = pk[ki], qi = qk[ki], pj = pk[kj], qj = qk[kj];
                        float a  = S[pi][pj], b  = S[pi][qj];
                        float c2 = S[qi][pj], d  = S[qi][qj];
                        float a1 = cj_ * a  - sj_ * b,  b1 = sj_ * a  + cj_ * b;
                        float c1 = cj_ * c2 - sj_ * d,  d1 = sj_ * c2 + cj_ * d;
                        S[pi][pj] = ci_ * a1 - si_ * c1;
                        S[qi][pj] = si_ * a1 + ci_ * c1;
                        S[pi][qj] = ci_ * b1 - si_ * d1;
                        S[qi][qj] = si_ * b1 + ci_ * d1;
                    }
                    // V <- V * J (register resident: lane = column, shfl p<->q)
                    {
                        int k;
                        if (lane == 0) k = 0;
                        else { int t = lane - 1 - r2; if (t < 0) t += 63;
                               k = (t <= 30) ? (t + 1) : (62 - t); }
                        float s_ = csS[k];
                        if (s_ != 0.f) {
                            float c_ = csC[k];
                            int p = pk[k], q = qk[k];
                            bool isp = (lane == p);
                            int part = isp ? q : p;
                            #pragma unroll
                            for (int i = 0; i < 8; ++i) {
                                float other = __shfl(v[i], part);
                                v[i] = isp ? (c_ * v[i] - s_ * other)
                                           : (s_ * other + c_ * v[i]);
                            }
                        }
                    }
                    __syncthreads();
                }
                // publish V: LDS (own apply) + Vbuf (other 15 chunks)
                float* vb = Vbuf + ((size_t)gpair << 12);
                #pragma unroll
                for (int i = 0; i < 8; ++i) {
                    Vs[8 * wv + i][lane] = v[i];
                    cst1(vb + (8 * wv + i) * 64 + lane, v[i]);
                }
                waitvm0();                 // every wave drains its V stores
                __syncthreads();
                if (tid == 0) ast(&vstat[gpair * 32], pphase * 2 + 1);
            }
        } else {
            // ---- non-solver: poll for V publication ----
            if (tid == 0) {
                int v;
                while ((v = ald(&vstat[gpair * 32])) < pphase * 2)
                    __builtin_amdgcn_s_sleep(4);
                active = v & 1;
            }
            __syncthreads();
            if (active) {
                do_apply = 1;
                const float* vb = Vbuf + ((size_t)gpair << 12);
                vf4 a0 = cld4(vb + 4 * tid);
                vf4 a1 = cld4(vb + 4 * (tid + 512));
                waitvm0();
                int i0 = tid >> 4, j0 = (tid & 15) << 2;
                int i1 = (tid + 512) >> 4;
                *(vf4*)&Vs[i0][j0] = a0;
                *(vf4*)&Vs[i1][j0] = a1;
                __syncthreads();
            }
        }

        // ---------------- phase C: apply (TT from A, Vs from B) -------------
        if (do_apply) {
            int rt = tid & 31, ct = tid >> 5;
            int rr0 = rt << 2, c20 = ct << 2;
            float acc[4][4] = {};
            for (int c = 0; c < 64; ++c) {
                float a[4], b[4];
                *(float4*)a = *(const float4*)&TT[c][rr0];
                *(float4*)b = *(const float4*)&Vs[c][c20];
                #pragma unroll
                for (int i = 0; i < 4; ++i)
                    #pragma unroll
                    for (int j = 0; j < 4; ++j)
                        acc[i][j] += a[i] * b[j];
            }
            __syncthreads();           // everyone done reading TT
            #pragma unroll
            for (int j = 0; j < 4; ++j)
                #pragma unroll
                for (int i = 0; i < 4; ++i)
                    TT[c20 + j][rr0 + i] = acc[i][j];
            __syncthreads();
            {
                int q  = tid & 31, r4 = q << 2;
                int cA = tid >> 5;
                cst4(W + (size_t)(gp * 32 + cA     ) * NN + r0 + r4, *(const vf4*)&TT[cA     ][r4]);
                cst4(W + (size_t)(gp * 32 + cA + 16) * NN + r0 + r4, *(const vf4*)&TT[cA + 16][r4]);
                cst4(W + (size_t)(gq * 32 + cA     ) * NN + r0 + r4, *(const vf4*)&TT[cA + 32][r4]);
                cst4(W + (size_t)(gq * 32 + cA + 16) * NN + r0 + r4, *(const vf4*)&TT[cA + 48][r4]);
            }
        }
        gridbar(bars, ++gphase);
        if (ald(&gctl[0])) break;
    }
}

// --------------------- norms, selection, gather -----------------------------
__global__ void colnorms(const float* __restrict__ W, float* __restrict__ sig2)
{
    __shared__ float red[256];
    int col = blockIdx.x, tid = threadIdx.x;
    const float* c = W + (size_t)col * NN;
    float s = 0.f;
    for (int e = tid; e < NN; e += 256) s += c[e] * c[e];
    red[tid] = s; __syncthreads();
    for (int off = 128; off; off >>= 1) { if (tid < off) red[tid] += red[tid + off]; __syncthreads(); }
    if (tid == 0) sig2[col] = red[0];
}

__global__ void select_k(const float* __restrict__ sig2, int* __restrict__ sel)
{
    int i = blockIdx.x * 256 + threadIdx.x;
    if (i >= NN) return;
    float di = sig2[i]; int rank = 0;
    for (int j = 0; j < NN; ++j) {
        float dj = sig2[j];
        rank += (dj < di) || (dj == di && j < i);
    }
    if (rank < LL) sel[rank] = i;
}

__global__ void gather_M(const float* __restrict__ W, const float* __restrict__ sig2,
                         const int* __restrict__ sel, const int* __restrict__ occ,
                         float* __restrict__ Mt)
{
    int idx = blockIdx.x * 256 + threadIdx.x;
    int b = idx >> 10, a = idx & (LL - 1);
    int col = sel[b];
    float rn = 1.f / sqrtf(sig2[col]);
    Mt[(size_t)b * LL + a] = W[(size_t)col * NN + occ[a]] * rn;
}

// G = Mt^T * Mt in fp64 (= M M^T)
__global__ void gram(const float* __restrict__ Mt, double* __restrict__ G)
{
    __shared__ float As[32][17], Bs[32][17];
    int t = threadIdx.x;
    int tx = t & 15, ty = t >> 4;
    int a0 = blockIdx.y * 16, c0 = blockIdx.x * 16;
    double s = 0.0;
    for (int kb = 0; kb < LL; kb += 32) {
        for (int u = t; u < 32 * 16; u += 256) {
            int kr = u >> 4, i = u & 15;
            As[kr][i] = Mt[(size_t)(kb + kr) * LL + a0 + i];
            Bs[kr][i] = Mt[(size_t)(kb + kr) * LL + c0 + i];
        }
        __syncthreads();
        #pragma unroll 8
        for (int k2 = 0; k2 < 32; ++k2)
            s += (double)As[k2][ty] * (double)Bs[k2][tx];
        __syncthreads();
    }
    G[(size_t)(a0 + ty) * LL + (c0 + tx)] = s;
}

// --------------------- blocked fp64 Cholesky (panel 64) ---------------------
__global__ void chol_panel(double* __restrict__ G, int k0, double* __restrict__ acc)
{
    __shared__ double Ld[64][65];
    __shared__ double sinv;
    int tid = threadIdx.x;
    for (int u = tid; u < 4096; u += 256)
        Ld[u >> 6][u & 63] = G[(size_t)(k0 + (u >> 6)) * LL + k0 + (u & 63)];
    __syncthreads();
    double lsum = 0.0;
    for (int c = 0; c < 64; ++c) {
        if (tid == 0) {
            double d = Ld[c][c]; d = d > 1e-300 ? d : 1e-300;
            double sd = sqrt(d); lsum += log(sd);
            Ld[c][c] = sd; sinv = 1.0 / sd;
        }
        __syncthreads();
        if (tid < 63 - c) Ld[c + 1 + tid][c] *= sinv;
        __syncthreads();
        for (int u = tid; u < 4096; u += 256) {
            int rr = u >> 6, cc = u & 63;
            if (rr > c && cc > c) Ld[rr][cc] -= Ld[rr][c] * Ld[cc][c];
        }
        __syncthreads();
    }
    for (int u = tid; u < 4096; u += 256)
        G[(size_t)(k0 + (u >> 6)) * LL + k0 + (u & 63)] = Ld[u >> 6][u & 63];
    if (tid == 0) atomicAdd(acc + 1, lsum);
}

__global__ void chol_trsm(double* __restrict__ G, int k0)
{
    __shared__ double L11[64][65];
    __shared__ double Rt[32][65];
    int tid = threadIdx.x;
    int rbase = k0 + 64 + blockIdx.x * 32;
    for (int u = tid; u < 4096; u += 256)
        L11[u >> 6][u & 63] = G[(size_t)(k0 + (u >> 6)) * LL + k0 + (u & 63)];
    for (int u = tid; u < 2048; u += 256)
        Rt[u >> 6][u & 63] = G[(size_t)(rbase + (u >> 6)) * LL + k0 + (u & 63)];
    __syncthreads();
    for (int c = 0; c < 64; ++c) {
        if (tid < 32) Rt[tid][c] *= 1.0 / L11[c][c];
        __syncthreads();
        for (int u = tid; u < 2048; u += 256) {
            int rr = u >> 6, cc = u & 63;
            if (cc > c) Rt[rr][cc] -= Rt[rr][c] * L11[cc][c];
        }
        __syncthreads();
    }
    for (int u = tid; u < 2048; u += 256)
        G[(size_t)(rbase + (u >> 6)) * LL + k0 + (u & 63)] = Rt[u >> 6][u & 63];
}

__global__ void chol_syrk(double* __restrict__ G, int k0)
{
    __shared__ double At[64][32];
    __shared__ double Bt[64][32];
    int tid = threadIdx.x;
    int r0g = k0 + 64 + blockIdx.y * 64;
    int c0g = k0 + 64 + blockIdx.x * 64;
    int i0 = (tid >> 4) << 2, j0 = (tid & 15) << 2;
    double acc[4][4] = {};
    for (int kh = 0; kh < 2; ++kh) {
        for (int u = tid; u < 2048; u += 256) {
            int i = u >> 5, c = u & 31;
            At[i][c] = G[(size_t)(r0g + i) * LL + k0 + kh * 32 + c];
            Bt[i][c] = G[(size_t)(c0g + i) * LL + k0 + kh * 32 + c];
        }
        __syncthreads();
        for (int c = 0; c < 32; ++c) {
            int cr = (c + tid) & 31;
            double a[4], b[4];
            #pragma unroll
            for (int i = 0; i < 4; ++i) a[i] = At[i0 + i][cr];
            #pragma unroll
            for (int j = 0; j < 4; ++j) b[j] = Bt[j0 + j][cr];
            #pragma unroll
            for (int i = 0; i < 4; ++i)
                #pragma unroll
                for (int j = 0; j < 4; ++j)
                    acc[i][j] += a[i] * b[j];
        }
        __syncthreads();
    }
    #pragma unroll
    for (int i = 0; i < 4; ++i)
        #pragma unroll
        for (int j = 0; j < 4; ++j) {
            size_t e = (size_t)(r0g + i0 + i) * LL + c0g + j0 + j;
            G[e] -= acc[i][j];
        }
}

// --------- all O(L^2) circulant quadratic forms + coherent terms ------------
__global__ void pair_sums(const float* __restrict__ Sz,  const float* __restrict__ X,
                          const float* __restrict__ Y,
                          const float* __restrict__ Jsp, const float* __restrict__ JXel,
                          const float* __restrict__ JYel,const float* __restrict__ pXX,
                          const float* __restrict__ pXY, const float* __restrict__ pYY,
                          const float* __restrict__ sb,  const float* __restrict__ stx,
                          const float* __restrict__ sty,
                          const float* __restrict__ zx,  const float* __restrict__ zy,
                          const float* __restrict__ xr,  const float* __restrict__ yr,
                          double* __restrict__ acc)
{
    __shared__ float tS[289], tXe[289], tYe[289], tXX[289], tXY[289], tYY[289];
    __shared__ double red[256];
    int tid = threadIdx.x;
    for (int u = tid; u < 289; u += 256) {
        tS[u]  = (u < 288) ? Jsp[u] : 0.f;
        tXX[u] = (u < 288) ? pXX[u] : 0.f;
        tXY[u] = (u < 288) ? pXY[u] : 0.f;
        tYY[u] = (u < 288) ? pYY[u] : 0.f;
        tXe[u] = (u >= 1 && u < 288) ? JXel[u - 1] : 0.f;
        tYe[u] = (u >= 1 && u < 288) ? JYel[u - 1] : 0.f;
    }
    __syncthreads();
    int idx = blockIdx.x * 256 + tid;
    int i = idx >> 10, j = idx & (LL - 1);
    int xi = i >> 5, yi = i & 31, xj = j >> 5, yj = j & 31;
    int dx = (xj - xi) & 31, dy = (yj - yi) & 31;
    int rx = (dx <= 16) ? dx : 32 - dx;
    int ry = (dy <= 16) ? dy : 32 - dy;
    int ti = rx * 17 + ry;
    float si = Sz[i], sj = Sz[j];
    float Xi = X[i], Xj = X[j], Yi = Y[i], Yj = Y[j];
    float sbij = sb[i * LL + j];
    double sum = (double)(si * sj) * (double)tS[ti];
    sum += (double)(Xi * Xj) * (double)tXX[ti];
    sum += (double)(Yi * Xj + Xi * Yj) * (double)tXY[ti];
    sum += (double)(Yi * Yj) * (double)tYY[ti];
    sum += (double)(si * sj * sbij) *
           ((double)tXe[ti] * (double)(Xi - Xj) + (double)tYe[ti] * (double)(Yi - Yj));
    if (i == j) {
        float ex = Xi - zx[0] * stx[i];
        float ey = Yi - zy[0] * sty[i];
        sum -= 0.5 * (double)xr[0] * ex * ex + 0.5 * (double)yr[0] * ey * ey;
    }
    red[tid] = sum; __syncthreads();
    for (int off = 128; off; off >>= 1) { if (tid < off) red[tid] += red[tid + off]; __syncthreads(); }
    if (tid == 0) atomicAdd(&acc[0], red[0]);
}

__global__ void finalize(const double* __restrict__ acc, float* __restrict__ out)
{
    out[0] = (float)(acc[0] + acc[1]);
}

// ---------------------------------------------------------------------------
extern "C" void kernel_launch(void* const* d_in, const int* in_sizes, int n_in,
                              void* d_out, int out_size, void* d_ws, size_t ws_size,
                              hipStream_t stream)
{
    const int*   occ  = (const int*)  d_in[0];
    const float* Sz   = (const float*)d_in[2];
    const float* X    = (const float*)d_in[3];
    const float* Y    = (const float*)d_in[4];
    const float* hv   = (const float*)d_in[5];
    const float* sv   = (const float*)d_in[6];
    const float* dv   = (const float*)d_in[7];
    const float* Jsp  = (const float*)d_in[8];
    const float* JXel = (const float*)d_in[9];
    const float* JYel = (const float*)d_in[10];
    const float* pXX  = (const float*)d_in[11];
    const float* pXY  = (const float*)d_in[12];
    const float* pYY  = (const float*)d_in[13];
    const float* g    = (const float*)d_in[14];
    const float* fS   = (const float*)d_in[15];
    const float* fd   = (const float*)d_in[16];
    const float* zx   = (const float*)d_in[17];
    const float* zy   = (const float*)d_in[18];
    const float* xr   = (const float*)d_in[19];
    const float* yr   = (const float*)d_in[20];
    const float* hop  = (const float*)d_in[21];
    const float* swm  = (const float*)d_in[22];
    const float* dwm  = (const float*)d_in[23];
    const int*   ivic = (const int*)  d_in[24];
    const float* sb   = (const float*)d_in[25];
    const float* stx  = (const float*)d_in[26];
    const float* sty  = (const float*)d_in[27];
    float* out = (float*)d_out;

    char* ws = (char*)d_ws;
    float*  W    = (float*) (ws + 0);           // 16.78 MB
    float*  v0   = (float*) (ws + 16777216);    // 8 KB
    float*  v1   = (float*) (ws + 16785408);    // 4 KB used
    float*  sig2 = (float*) (ws + 16793600);
    int*    sel  = (int*)   (ws + 16801792);
    float*  Mt   = (float*) (ws + 16805888);    // 4 MB; first ~700KB doubles as barrier/V region during Jacobi
    double* G    = (double*)(ws + 21000192);    // 8 MB fp64 Gram; first 1MB doubles as Sg (fp32) during Jacobi
    double* acc  = (double*)(ws + 29388800);    // 32 doubles
    int*    gctl = (int*)   (ws + 29389056);    // [0]=gconv [1]=streak [2..65]=clean
    int*    bars  = (int*)  Mt;                 // global barrier: 10 x 4KB-spaced words (40KB)
    int*    pbars = bars + 10 * 1024;           // pair arrival counters: 32 x 4KB-spaced (128KB)
    int*    vstat = pbars + 32 * 1024;          // V-publication seq: 32 x 128B-spaced (4KB)
    float*  Vbuf  = (float*)(vstat + 1024);     // 32 pairs x 4096 floats (512KB)
    float*  Sg    = (float*)G;                  // 2 x 32 x 4096 floats, double-buffered

    (void)hipMemsetAsync(acc, 0, 768, stream);              // acc + gctl
    (void)hipMemsetAsync(bars, 0, 44 * 4096, stream);       // bars + pbars + vstat
    (void)hipMemsetAsync(Sg, 0, 2 * 32 * 4096 * 4, stream); // Sg both parity buffers
    build_H<<<NN * NN / 256, 256, 0, stream>>>(hop, swm, dwm, hv, sv, dv, X, Y,
                                               ivic, sb, g, fS, fd, W);
    powv_init<<<8, 256, 0, stream>>>(v0);
    for (int it = 0; it < PITER; ++it) {
        const float* vin = (it & 1) ? v1 : v0;
        float* vout = (it & 1) ? v0 : v1;
        matvec<<<NN, 256, 0, stream>>>(W, vin, vout, acc + 8 + it);
    }
    add_shift<<<8, 256, 0, stream>>>(W, acc);

    // single persistent kernel for all NSWB*63 Jacobi rounds
    jac_fused<<<512, 512, 0, stream>>>(W, Sg, Vbuf, gctl, bars, pbars, vstat);

    colnorms<<<NN, 256, 0, stream>>>(W, sig2);
    select_k<<<8, 256, 0, stream>>>(sig2, sel);
    gather_M<<<4096, 256, 0, stream>>>(W, sig2, sel, occ, Mt);
    gram<<<dim3(64, 64), 256, 0, stream>>>(Mt, G);

    for (int s = 0; s < 16; ++s) {
        int k0 = s * 64;
        chol_panel<<<1, 256, 0, stream>>>(G, k0, acc);
        int nrows = LL - k0 - 64;
        if (nrows > 0) {
            chol_trsm<<<nrows / 32, 256, 0, stream>>>(G, k0);
            chol_syrk<<<dim3(nrows / 64, nrows / 64), 256, 0, stream>>>(G, k0);
        }
    }

    pair_sums<<<4096, 256, 0, stream>>>(Sz, X, Y, Jsp, JXel, JYel, pXX, pXY, pYY,
                                        sb, stx, sty, zx, zy, xr, yr, acc);
    finalize<<<1, 1, 0, stream>>>(acc, out);
}

// Round 10
// 62505.109 us; speedup vs baseline: 1.1801x; 1.0224x over previous
//
#include <hip/hip_runtime.h>
#include <math.h>

#define NN 2048   // 2L
#define LL 1024   // L
#define NSWB 8    // blocked Jacobi sweeps
#define NROUNDS (NSWB * 63)
#define PITER 10  // power iterations for spectral radius
#define JTAU 1e-6f   // relative off^2 threshold (|apq|_rel < 1e-3 -> identity).
                     // logdet is 2nd-order stationary in subspace rotations:
                     // error ~ 1024*theta^2 ~ 1e-3 at theta=1e-3, vs threshold
                     // 15.76 (absmax was 0.0 at 1e-8 -> huge headroom). Looser
                     // tau => earlier clean-detect, shorter inner sweeps,
                     // earlier gconv => fewer/cheaper rounds.
#define STREAK_FULL 2016   // 63 rounds x 32 pairs all-skip = one clean sweep

// gctl layout (ints, zeroed at launch): [0]=gconv [1]=streak [2..65]=clean[64]

typedef float vf4 __attribute__((ext_vector_type(4)));   // asm-friendly reg quad

// ---------------------------------------------------------------------------
__global__ void build_H(const float* __restrict__ hop,  const float* __restrict__ swm,
                        const float* __restrict__ dwm,  const float* __restrict__ hv,
                        const float* __restrict__ sv,   const float* __restrict__ dv,
                        const float* __restrict__ X,    const float* __restrict__ Y,
                        const int*   __restrict__ ivic, const float* __restrict__ sb,
                        const float* __restrict__ gg,   const float* __restrict__ fS,
                        const float* __restrict__ fd,   float* __restrict__ W)
{
    int idx = blockIdx.x * 256 + threadIdx.x;
    int r = idx >> 11, c = idx & (NN - 1);
    float hv0 = hv[0], hv1 = hv[1], sv0 = sv[0], dv0 = dv[0];
    float g0 = gg[0], fS0 = fS[0], fd0 = fd[0];

    float val = 0.f;
    #pragma unroll
    for (int t = 0; t < 2; ++t) {
        int rr = t ? c : r;
        int cc = t ? r : c;
        int e  = rr * NN + cc;
        float v = hv0 * hop[e] - hop[NN*NN + e] + hv1 * hop[2*NN*NN + e]
                + sv0 * swm[e] + dv0 * dwm[e];
        int i = rr & (LL - 1), j = cc & (LL - 1);
        float px = 0.f, py = 0.f;
        float s = sb[i * LL + j];
        int n0 = ivic[i*4+0], n1 = ivic[i*4+1], n2 = ivic[i*4+2], n3 = ivic[i*4+3];
        if (j == n1 || j == n3) px = (X[j] - X[i]) * s;
        if (j == n0 || j == n2) py = (Y[j] - Y[i]) * s;
        float P = px + py, Mm = px - py;
        bool rlo = rr < LL, clo = cc < LL;
        if (rlo && clo)        v += g0 * P;
        else if (!rlo && !clo) v -= g0 * P;
        else                   v += fS0 * P + fd0 * Mm;
        val += 0.5f * v;
    }
    W[idx] = val;
}

// --------------------- power iteration for spectral radius ------------------
__global__ void powv_init(float* v)
{
    int i = blockIdx.x * 256 + threadIdx.x;
    if (i < NN) {
        unsigned h = (unsigned)i * 2654435761u;
        h ^= h >> 13; h *= 2246822519u; h ^= h >> 16;
        v[i] = ((h >> 8) * (1.0f / 16777216.f)) - 0.5f;
    }
}

__global__ void matvec(const float* __restrict__ W, const float* __restrict__ vin,
                       float* __restrict__ vout, double* accslot)
{
    __shared__ float red[256];
    int row = blockIdx.x, tid = threadIdx.x;
    const float* wr = W + (size_t)row * NN;
    float s = 0.f;
    for (int j = tid; j < NN; j += 256) s += wr[j] * vin[j];
    red[tid] = s; __syncthreads();
    for (int off = 128; off; off >>= 1) { if (tid < off) red[tid] += red[tid + off]; __syncthreads(); }
    if (tid == 0) { float y = red[0]; vout[row] = y; atomicAdd(accslot, (double)y * (double)y); }
}

__global__ void add_shift(float* W, const double* acc)
{
    int i = blockIdx.x * 256 + threadIdx.x;
    if (i < NN) {
        double n1 = acc[8 + PITER - 1], n0 = acc[8 + PITER - 2];
        float rho = (float)sqrt(n1 / (n0 > 0.0 ? n0 : 1.0));
        W[(size_t)i * NN + i] += 1.45f * rho;
    }
}

// ------------------- blocked Jacobi: fused persistent kernel ----------------
__device__ __forceinline__ void pair_groups(int pair, int r, int& gp, int& gq)
{
    if (pair == 0) gp = 0;
    else { int t1 = pair - 1 + r; if (t1 >= 63) t1 -= 63; gp = 1 + t1; }
    int t2 = 62 - pair + r; if (t2 >= 63) t2 -= 63; gq = 1 + t2;
}

// Fence-free coherence discipline (proven in v3/v5/v7): all cross-block
// traffic uses IF$-coherent accesses (sc0 sc1 / relaxed agent atomics); NO
// acquire/release fences -> no buffer_wbl2/inv. Ordering is manual: every
// wave drains vmcnt(0) before its block's barrier arrival / flag publish.
__device__ __forceinline__ int  ald(const int* p)
{ return __hip_atomic_load(p, __ATOMIC_RELAXED, __HIP_MEMORY_SCOPE_AGENT); }
__device__ __forceinline__ void ast(int* p, int v)
{ __hip_atomic_store(p, v, __ATOMIC_RELAXED, __HIP_MEMORY_SCOPE_AGENT); }
__device__ __forceinline__ void afst(float* p, float v)
{ __hip_atomic_store(p, v, __ATOMIC_RELAXED, __HIP_MEMORY_SCOPE_AGENT); }
__device__ __forceinline__ void afadd(float* p, float v)
{ (void)__hip_atomic_fetch_add(p, v, __ATOMIC_RELAXED, __HIP_MEMORY_SCOPE_AGENT); }

// IF$-coherent load/store (single-writer data; atomicity not required,
// only coherence + manual ordering). ext_vector_type maps to a VGPR quad.
__device__ __forceinline__ vf4 cld4(const float* p)
{ vf4 d; asm volatile("global_load_dwordx4 %0, %1, off sc0 sc1" : "=v"(d) : "v"(p)); return d; }
__device__ __forceinline__ void cst4(float* p, vf4 v)
{ asm volatile("global_store_dwordx4 %0, %1, off sc0 sc1" :: "v"(p), "v"(v) : "memory"); }
__device__ __forceinline__ void cst1(float* p, float v)
{ asm volatile("global_store_dword %0, %1, off sc0 sc1" :: "v"(p), "v"(v) : "memory"); }
__device__ __forceinline__ void waitvm0()
{ asm volatile("s_waitcnt vmcnt(0)" ::: "memory"); __builtin_amdgcn_sched_barrier(0); }

// global tree barrier, fence-free. Words spaced 4KB apart; XCD-local
// sub-counters. ALL waves drain vmcnt before arrival.
__device__ __forceinline__ void gridbar(int* bars, int phase)
{
    waitvm0();
    __syncthreads();
    if (threadIdx.x == 0) {
        int g = blockIdx.x & 7;
        int old = __hip_atomic_fetch_add(&bars[g * 1024], 1,
                      __ATOMIC_RELAXED, __HIP_MEMORY_SCOPE_AGENT);
        if (old == phase * 64 - 1) {                       // group leader
            int t = __hip_atomic_fetch_add(&bars[8 * 1024], 1,
                        __ATOMIC_RELAXED, __HIP_MEMORY_SCOPE_AGENT);
            if (t == phase * 8 - 1)                        // global last
                ast(&bars[9 * 1024], phase);
        }
        while (ald(&bars[9 * 1024]) < phase)
            __builtin_amdgcn_s_sleep(8);
        asm volatile("" ::: "memory");
    }
    __syncthreads();
}

// One kernel for all NSWB*63 rounds, 512 blocks x 512 threads (2/CU by LDS).
// Per round, block (pair,chunk) = (bid>>4, bid&15); solver chunk = pair>>1
// (guarantees no two solver blocks co-reside on one CU under round-robin
// dispatch: co-residents are (b, b+256), and solver ids 16p+(p>>1) vs
// 16(p+16)+((p+16)>>1) differ by 264, never 256).
//   A: zero next-round Sg slice; stage own 64x128 W tile -> TT; partial
//      Gram; global_atomic_add_f32 into Sg[rr&1][pair]; arrive at pbars.
//   B: SOLVER spins for 16 arrivals, reduces Sg -> S, runs the inner-sweep
//      solve (V in registers), writes Vbuf + publishes vstat = pphase*2+act.
//      NON-SOLVERS poll vstat, then read Vbuf -> Vs. No redundant solve ->
//      one solver per CU, private LDS pipe.
//   C: apply TT x V -> W tile (TT reused from A).
//   [global barrier]; uniform convergence break on gctl[0].
// hint is pair-uniform: gctl group words are written only by the owning
// pair's solver in phase B (vmcnt-drained before the end-of-round gridbar)
// and read at round start after the gridbar -> all 16 chunks agree, so
// pphase stays lockstep across the pair (no protocol divergence).
__global__ __launch_bounds__(512, 4) void jac_fused(float* __restrict__ W,
                                                    float* __restrict__ Sg,
                                                    float* __restrict__ Vbuf,
                                                    int* __restrict__ gctl,
                                                    int* __restrict__ bars,
                                                    int* __restrict__ pbars,
                                                    int* __restrict__ vstat)
{
    __shared__ float TT[64][132];   // A/C: 64-col x 128-row W tile
    __shared__ float S[64][65];     // B(solver): pair Gram
    __shared__ float Vs[64][64];    // B->C: V tile
    __shared__ float csC[32], csS[32];
    __shared__ int   pk[32], qk[32];
    __shared__ int   active;
    __shared__ int   nact[2];

    const int tid    = threadIdx.x;
    const int bid    = blockIdx.x;
    const int gpair  = bid >> 4, chunk = bid & 15;
    const int r0     = chunk * 128;
    const bool issol = (chunk == (gpair >> 1));
    const bool ldr   = (issol && tid == 0);      // single writer for gctl
    int gphase = 0, pphase = 0;

    for (int rr = 0; rr < NROUNDS; ++rr) {
        int r = rr; while (r >= 63) r -= 63;
        int gp, gq; pair_groups(gpair, r, gp, gq);
        int c1 = ald(&gctl[2 + gp]);
        int c2 = ald(&gctl[2 + gq]);
        bool hint = (c1 >= 63 && c2 >= 63);
        if (!hint) ++pphase;                     // lockstep across the pair

        // zero next-round Sg slice (last readers were last round, separated
        // by the end-of-round gridbar)
        {
            float* bufn = Sg + ((size_t)(((rr + 1) & 1) * 32 + gpair)) * 4096 + chunk * 256;
            if (tid < 256) afst(&bufn[tid], 0.f);
        }

        // ---------------- phase A: stage + gram + accumulate ----------------
        if (!hint) {
            {
                int q  = tid & 31, r4 = q << 2;
                int cA = tid >> 5;
                vf4 t0 = cld4(W + (size_t)(gp * 32 + cA     ) * NN + r0 + r4);
                vf4 t1 = cld4(W + (size_t)(gp * 32 + cA + 16) * NN + r0 + r4);
                vf4 t2 = cld4(W + (size_t)(gq * 32 + cA     ) * NN + r0 + r4);
                vf4 t3 = cld4(W + (size_t)(gq * 32 + cA + 16) * NN + r0 + r4);
                waitvm0();
                *(vf4*)&TT[cA     ][r4] = t0;
                *(vf4*)&TT[cA + 16][r4] = t1;
                *(vf4*)&TT[cA + 32][r4] = t2;
                *(vf4*)&TT[cA + 48][r4] = t3;
            }
            __syncthreads();
            int tr = tid & 15, tc = tid >> 4;
            float acc[4][2] = {};
            for (int r4 = 0; r4 < 128; r4 += 4) {
                float a[4][4], b[2][4];
                #pragma unroll
                for (int m = 0; m < 4; ++m) *(float4*)a[m] = *(const float4*)&TT[tr + 16*m][r4];
                #pragma unroll
                for (int n = 0; n < 2; ++n) *(float4*)b[n] = *(const float4*)&TT[tc + 32*n][r4];
                #pragma unroll
                for (int m = 0; m < 4; ++m)
                    #pragma unroll
                    for (int n = 0; n < 2; ++n)
                        #pragma unroll
                        for (int k = 0; k < 4; ++k)
                            acc[m][n] += a[m][k] * b[n][k];
            }
            float* bufc = Sg + ((size_t)((rr & 1) * 32 + gpair)) * 4096;
            #pragma unroll
            for (int m = 0; m < 4; ++m)
                #pragma unroll
                for (int n = 0; n < 2; ++n)
                    afadd(&bufc[(tr + 16*m) * 64 + (tc + 32*n)], acc[m][n]);
            waitvm0();                 // every wave drains its Sg adds
            __syncthreads();
            if (tid == 0)
                (void)__hip_atomic_fetch_add(&pbars[gpair * 1024], 1,
                          __ATOMIC_RELAXED, __HIP_MEMORY_SCOPE_AGENT);
        }

        // ---------------- phase B ----------------
        int do_apply = 0;
        if (hint) {
            if (ldr) {
                ast(&gctl[2 + gp], c1 + 1);
                ast(&gctl[2 + gq], c2 + 1);
                int old = __hip_atomic_fetch_add(&gctl[1], 1,
                              __ATOMIC_RELAXED, __HIP_MEMORY_SCOPE_AGENT);
                if (old + 1 >= STREAK_FULL) ast(&gctl[0], 1);
            }
        } else if (issol) {
            // ---- solver: wait for all 16 Gram contributions ----
            if (tid == 0) {
                while (ald(&pbars[gpair * 1024]) < 16 * pphase)
                    __builtin_amdgcn_s_sleep(4);
                active = 0;
            }
            if (tid < 2) nact[tid] = 0;
            __syncthreads();
            {
                const float* bufc = Sg + ((size_t)((rr & 1) * 32 + gpair)) * 4096;
                vf4 s0 = cld4(bufc + 4 * tid);
                vf4 s1 = cld4(bufc + 4 * (tid + 512));
                waitvm0();
                int i0 = tid >> 4, j0 = (tid & 15) << 2;
                int i1 = (tid + 512) >> 4;
                S[i0][j0] = s0.x; S[i0][j0+1] = s0.y; S[i0][j0+2] = s0.z; S[i0][j0+3] = s0.w;
                S[i1][j0] = s1.x; S[i1][j0+1] = s1.y; S[i1][j0+2] = s1.z; S[i1][j0+3] = s1.w;
            }
            __syncthreads();
            int loc = 0;
            for (int e = tid; e < 4096; e += 512) {
                int i = e >> 6, j = e & 63;
                if (i < j) {
                    float o = S[i][j];
                    if (o * o > JTAU * S[i][i] * S[j][j]) loc = 1;
                }
            }
            if (loc) active = 1;          // benign race: only ever set to 1
            __syncthreads();
            if (!active) {
                if (tid == 0) {
                    ast(&gctl[2 + gp], c1 + 1);
                    ast(&gctl[2 + gq], c2 + 1);
                    int old = __hip_atomic_fetch_add(&gctl[1], 1,
                                  __ATOMIC_RELAXED, __HIP_MEMORY_SCOPE_AGENT);
                    if (old + 1 >= STREAK_FULL) ast(&gctl[0], 1);
                    ast(&vstat[gpair * 32], pphase * 2);     // publish: identity
                }
            } else {
                do_apply = 1;
                if (tid == 0) {
                    ast(&gctl[2 + gp], 0);
                    ast(&gctl[2 + gq], 0);
                    __hip_atomic_exchange(&gctl[1], 0,
                        __ATOMIC_RELAXED, __HIP_MEMORY_SCOPE_AGENT);
                }
                int lane = tid & 63, wv = tid >> 6;   // 8 waves; wave w owns V rows 8w..8w+7
                float v[8];
                #pragma unroll
                for (int i = 0; i < 8; ++i) v[i] = (8 * wv + i == lane) ? 1.f : 0.f;

                for (int r2 = 0; r2 < 63; ++r2) {
                    if (tid < 32) {
                        int k = tid, p, q;
                        if (k == 0) p = 0;
                        else { int t1 = k - 1 + r2; if (t1 >= 63) t1 -= 63; p = 1 + t1; }
                        int t2 = 62 - k + r2; if (t2 >= 63) t2 -= 63; q = 1 + t2;
                        float app = S[p][p], aqq = S[q][q], apq = S[p][q];
                        float c = 1.f, s = 0.f;
                        if (apq * apq > JTAU * app * aqq) {
                            // fast-math chain (~1e-7 rel; Jacobi self-corrects)
                            float tau = (aqq - app) * __builtin_amdgcn_rcpf(2.f * apq);
                            float sq  = __builtin_amdgcn_sqrtf(fmaf(tau, tau, 1.f));
                            float t   = (tau >= 0.f ? 1.f : -1.f) *
                                        __builtin_amdgcn_rcpf(fabsf(tau) + sq);
                            c = __builtin_amdgcn_rsqf(fmaf(t, t, 1.f));
                            s = t * c;
                            nact[r2 & 1] = 1;     // benign multi-writer, same value
                        }
                        csC[k] = c; csS[k] = s; pk[k] = p; qk[k] = q;
                    }
                    if (tid == 256) nact[(r2 + 1) & 1] = 0;
                    __syncthreads();
                    if (!nact[r2 & 1]) break;
                    // one-pass S <- J^T S J over disjoint 2x2 blocks (2/thread)
                    for (int u = tid; u < 1024; u += 512) {
                        int ki = u >> 5, kj = u & 31;
                        float si_ = csS[ki], sj_ = csS[kj];
                        if (si_ == 0.f && sj_ == 0.f) continue;
                        float ci_ = csC[ki], cj_ = csC[kj];
                        int pi = pk[ki], qi = qk[ki], pj = pk[kj], qj = qk[kj];
                        float a  = S[pi][pj], b  = S[pi][qj];
                        float c2 = S[qi][pj], d  = S[qi][qj];
                        float a1 = cj_ * a  - sj_ * b,  b1 = sj_ * a  + cj_ * b;
                        float c1 = cj_ * c2 - sj_ * d,  d1 = sj_ * c2 + cj_ * d;
                        S[pi][pj] = ci_ * a1 - si_ * c1;
                        S[qi][pj] = si_ * a1 + ci_ * c1;
                        S[pi][qj] = ci_ * b1 - si_ * d1;
                        S[qi][qj] = si_ * b1 + ci_ * d1;
                    }
                    // V <- V * J (register resident: lane = column, shfl p<->q)
                    {
                        int k;
                        if (lane == 0) k = 0;
                        else { int t = lane - 1 - r2; if (t < 0) t += 63;
                               k = (t <= 30) ? (t + 1) : (62 - t); }
                        float s_ = csS[k];
                        if (s_ != 0.f) {
                            float c_ = csC[k];
                            int p = pk[k], q = qk[k];
                            bool isp = (lane == p);
                            int part = isp ? q : p;
                            #pragma unroll
                            for (int i = 0; i < 8; ++i) {
                                float other = __shfl(v[i], part);
                                v[i] = isp ? (c_ * v[i] - s_ * other)
                                           : (s_ * other + c_ * v[i]);
                            }
                        }
                    }
                    __syncthreads();
                }
                // publish V: LDS (own apply) + Vbuf (other 15 chunks)
                float* vb = Vbuf + ((size_t)gpair << 12);
                #pragma unroll
                for (int i = 0; i < 8; ++i) {
                    Vs[8 * wv + i][lane] = v[i];
                    cst1(vb + (8 * wv + i) * 64 + lane, v[i]);
                }
                waitvm0();                 // every wave drains its V stores
                __syncthreads();
                if (tid == 0) ast(&vstat[gpair * 32], pphase * 2 + 1);
            }
        } else {
            // ---- non-solver: poll for V publication ----
            if (tid == 0) {
                int v;
                while ((v = ald(&vstat[gpair * 32])) < pphase * 2)
                    __builtin_amdgcn_s_sleep(4);
                active = v & 1;
                asm volatile("" ::: "memory");
            }
            __syncthreads();
            if (active) {
                do_apply = 1;
                const float* vb = Vbuf + ((size_t)gpair << 12);
                vf4 a0 = cld4(vb + 4 * tid);
                vf4 a1 = cld4(vb + 4 * (tid + 512));
                waitvm0();
                int i0 = tid >> 4, j0 = (tid & 15) << 2;
                int i1 = (tid + 512) >> 4;
                *(vf4*)&Vs[i0][j0] = a0;
                *(vf4*)&Vs[i1][j0] = a1;
                __syncthreads();
            }
        }

        // ---------------- phase C: apply (TT from A, Vs from B) -------------
        if (do_apply) {
            int rt = tid & 31, ct = tid >> 5;
            int rr0 = rt << 2, c20 = ct << 2;
            float acc[4][4] = {};
            for (int c = 0; c < 64; ++c) {
                float a[4], b[4];
                *(float4*)a = *(const float4*)&TT[c][rr0];
                *(float4*)b = *(const float4*)&Vs[c][c20];
                #pragma unroll
                for (int i = 0; i < 4; ++i)
                    #pragma unroll
                    for (int j = 0; j < 4; ++j)
                        acc[i][j] += a[i] * b[j];
            }
            __syncthreads();           // everyone done reading TT
            #pragma unroll
            for (int j = 0; j < 4; ++j)
                #pragma unroll
                for (int i = 0; i < 4; ++i)
                    TT[c20 + j][rr0 + i] = acc[i][j];
            __syncthreads();
            {
                int q  = tid & 31, r4 = q << 2;
                int cA = tid >> 5;
                cst4(W + (size_t)(gp * 32 + cA     ) * NN + r0 + r4, *(const vf4*)&TT[cA     ][r4]);
                cst4(W + (size_t)(gp * 32 + cA + 16) * NN + r0 + r4, *(const vf4*)&TT[cA + 16][r4]);
                cst4(W + (size_t)(gq * 32 + cA     ) * NN + r0 + r4, *(const vf4*)&TT[cA + 32][r4]);
                cst4(W + (size_t)(gq * 32 + cA + 16) * NN + r0 + r4, *(const vf4*)&TT[cA + 48][r4]);
            }
        }
        gridbar(bars, ++gphase);
        if (ald(&gctl[0])) break;
    }
}

// --------------------- norms, selection, gather -----------------------------
__global__ void colnorms(const float* __restrict__ W, float* __restrict__ sig2)
{
    __shared__ float red[256];
    int col = blockIdx.x, tid = threadIdx.x;
    const float* c = W + (size_t)col * NN;
    float s = 0.f;
    for (int e = tid; e < NN; e += 256) s += c[e] * c[e];
    red[tid] = s; __syncthreads();
    for (int off = 128; off; off >>= 1) { if (tid < off) red[tid] += red[tid + off]; __syncthreads(); }
    if (tid == 0) sig2[col] = red[0];
}

__global__ void select_k(const float* __restrict__ sig2, int* __restrict__ sel)
{
    int i = blockIdx.x * 256 + threadIdx.x;
    if (i >= NN) return;
    float di = sig2[i]; int rank = 0;
    for (int j = 0; j < NN; ++j) {
        float dj = sig2[j];
        rank += (dj < di) || (dj == di && j < i);
    }
    if (rank < LL) sel[rank] = i;
}

__global__ void gather_M(const float* __restrict__ W, const float* __restrict__ sig2,
                         const int* __restrict__ sel, const int* __restrict__ occ,
                         float* __restrict__ Mt)
{
    int idx = blockIdx.x * 256 + threadIdx.x;
    int b = idx >> 10, a = idx & (LL - 1);
    int col = sel[b];
    float rn = 1.f / sqrtf(sig2[col]);
    Mt[(size_t)b * LL + a] = W[(size_t)col * NN + occ[a]] * rn;
}

// G = Mt^T * Mt in fp64 (= M M^T)
__global__ void gram(const float* __restrict__ Mt, double* __restrict__ G)
{
    __shared__ float As[32][17], Bs[32][17];
    int t = threadIdx.x;
    int tx = t & 15, ty = t >> 4;
    int a0 = blockIdx.y * 16, c0 = blockIdx.x * 16;
    double s = 0.0;
    for (int kb = 0; kb < LL; kb += 32) {
        for (int u = t; u < 32 * 16; u += 256) {
            int kr = u >> 4, i = u & 15;
            As[kr][i] = Mt[(size_t)(kb + kr) * LL + a0 + i];
            Bs[kr][i] = Mt[(size_t)(kb + kr) * LL + c0 + i];
        }
        __syncthreads();
        #pragma unroll 8
        for (int k2 = 0; k2 < 32; ++k2)
            s += (double)As[k2][ty] * (double)Bs[k2][tx];
        __syncthreads();
    }
    G[(size_t)(a0 + ty) * LL + (c0 + tx)] = s;
}

// --------------------- blocked fp64 Cholesky (panel 64) ---------------------
__global__ void chol_panel(double* __restrict__ G, int k0, double* __restrict__ acc)
{
    __shared__ double Ld[64][65];
    __shared__ double sinv;
    int tid = threadIdx.x;
    for (int u = tid; u < 4096; u += 256)
        Ld[u >> 6][u & 63] = G[(size_t)(k0 + (u >> 6)) * LL + k0 + (u & 63)];
    __syncthreads();
    double lsum = 0.0;
    for (int c = 0; c < 64; ++c) {
        if (tid == 0) {
            double d = Ld[c][c]; d = d > 1e-300 ? d : 1e-300;
            double sd = sqrt(d); lsum += log(sd);
            Ld[c][c] = sd; sinv = 1.0 / sd;
        }
        __syncthreads();
        if (tid < 63 - c) Ld[c + 1 + tid][c] *= sinv;
        __syncthreads();
        for (int u = tid; u < 4096; u += 256) {
            int rr = u >> 6, cc = u & 63;
            if (rr > c && cc > c) Ld[rr][cc] -= Ld[rr][c] * Ld[cc][c];
        }
        __syncthreads();
    }
    for (int u = tid; u < 4096; u += 256)
        G[(size_t)(k0 + (u >> 6)) * LL + k0 + (u & 63)] = Ld[u >> 6][u & 63];
    if (tid == 0) atomicAdd(acc + 1, lsum);
}

__global__ void chol_trsm(double* __restrict__ G, int k0)
{
    __shared__ double L11[64][65];
    __shared__ double Rt[32][65];
    int tid = threadIdx.x;
    int rbase = k0 + 64 + blockIdx.x * 32;
    for (int u = tid; u < 4096; u += 256)
        L11[u >> 6][u & 63] = G[(size_t)(k0 + (u >> 6)) * LL + k0 + (u & 63)];
    for (int u = tid; u < 2048; u += 256)
        Rt[u >> 6][u & 63] = G[(size_t)(rbase + (u >> 6)) * LL + k0 + (u & 63)];
    __syncthreads();
    for (int c = 0; c < 64; ++c) {
        if (tid < 32) Rt[tid][c] *= 1.0 / L11[c][c];
        __syncthreads();
        for (int u = tid; u < 2048; u += 256) {
            int rr = u >> 6, cc = u & 63;
            if (cc > c) Rt[rr][cc] -= Rt[rr][c] * L11[cc][c];
        }
        __syncthreads();
    }
    for (int u = tid; u < 2048; u += 256)
        G[(size_t)(rbase + (u >> 6)) * LL + k0 + (u & 63)] = Rt[u >> 6][u & 63];
}

__global__ void chol_syrk(double* __restrict__ G, int k0)
{
    __shared__ double At[64][32];
    __shared__ double Bt[64][32];
    int tid = threadIdx.x;
    int r0g = k0 + 64 + blockIdx.y * 64;
    int c0g = k0 + 64 + blockIdx.x * 64;
    int i0 = (tid >> 4) << 2, j0 = (tid & 15) << 2;
    double acc[4][4] = {};
    for (int kh = 0; kh < 2; ++kh) {
        for (int u = tid; u < 2048; u += 256) {
            int i = u >> 5, c = u & 31;
            At[i][c] = G[(size_t)(r0g + i) * LL + k0 + kh * 32 + c];
            Bt[i][c] = G[(size_t)(c0g + i) * LL + k0 + kh * 32 + c];
        }
        __syncthreads();
        for (int c = 0; c < 32; ++c) {
            int cr = (c + tid) & 31;
            double a[4], b[4];
            #pragma unroll
            for (int i = 0; i < 4; ++i) a[i] = At[i0 + i][cr];
            #pragma unroll
            for (int j = 0; j < 4; ++j) b[j] = Bt[j0 + j][cr];
            #pragma unroll
            for (int i = 0; i < 4; ++i)
                #pragma unroll
                for (int j = 0; j < 4; ++j)
                    acc[i][j] += a[i] * b[j];
        }
        __syncthreads();
    }
    #pragma unroll
    for (int i = 0; i < 4; ++i)
        #pragma unroll
        for (int j = 0; j < 4; ++j) {
            size_t e = (size_t)(r0g + i0 + i) * LL + c0g + j0 + j;
            G[e] -= acc[i][j];
        }
}

// --------- all O(L^2) circulant quadratic forms + coherent terms ------------
__global__ void pair_sums(const float* __restrict__ Sz,  const float* __restrict__ X,
                          const float* __restrict__ Y,
                          const float* __restrict__ Jsp, const float* __restrict__ JXel,
                          const float* __restrict__ JYel,const float* __restrict__ pXX,
                          const float* __restrict__ pXY, const float* __restrict__ pYY,
                          const float* __restrict__ sb,  const float* __restrict__ stx,
                          const float* __restrict__ sty,
                          const float* __restrict__ zx,  const float* __restrict__ zy,
                          const float* __restrict__ xr,  const float* __restrict__ yr,
                          double* __restrict__ acc)
{
    __shared__ float tS[289], tXe[289], tYe[289], tXX[289], tXY[289], tYY[289];
    __shared__ double red[256];
    int tid = threadIdx.x;
    for (int u = tid; u < 289; u += 256) {
        tS[u]  = (u < 288) ? Jsp[u] : 0.f;
        tXX[u] = (u < 288) ? pXX[u] : 0.f;
        tXY[u] = (u < 288) ? pXY[u] : 0.f;
        tYY[u] = (u < 288) ? pYY[u] : 0.f;
        tXe[u] = (u >= 1 && u < 288) ? JXel[u - 1] : 0.f;
        tYe[u] = (u >= 1 && u < 288) ? JYel[u - 1] : 0.f;
    }
    __syncthreads();
    int idx = blockIdx.x * 256 + tid;
    int i = idx >> 10, j = idx & (LL - 1);
    int xi = i >> 5, yi = i & 31, xj = j >> 5, yj = j & 31;
    int dx = (xj - xi) & 31, dy = (yj - yi) & 31;
    int rx = (dx <= 16) ? dx : 32 - dx;
    int ry = (dy <= 16) ? dy : 32 - dy;
    int ti = rx * 17 + ry;
    float si = Sz[i], sj = Sz[j];
    float Xi = X[i], Xj = X[j], Yi = Y[i], Yj = Y[j];
    float sbij = sb[i * LL + j];
    double sum = (double)(si * sj) * (double)tS[ti];
    sum += (double)(Xi * Xj) * (double)tXX[ti];
    sum += (double)(Yi * Xj + Xi * Yj) * (double)tXY[ti];
    sum += (double)(Yi * Yj) * (double)tYY[ti];
    sum += (double)(si * sj * sbij) *
           ((double)tXe[ti] * (double)(Xi - Xj) + (double)tYe[ti] * (double)(Yi - Yj));
    if (i == j) {
        float ex = Xi - zx[0] * stx[i];
        float ey = Yi - zy[0] * sty[i];
        sum -= 0.5 * (double)xr[0] * ex * ex + 0.5 * (double)yr[0] * ey * ey;
    }
    red[tid] = sum; __syncthreads();
    for (int off = 128; off; off >>= 1) { if (tid < off) red[tid] += red[tid + off]; __syncthreads(); }
    if (tid == 0) atomicAdd(&acc[0], red[0]);
}

__global__ void finalize(const double* __restrict__ acc, float* __restrict__ out)
{
    out[0] = (float)(acc[0] + acc[1]);
}

// ---------------------------------------------------------------------------
extern "C" void kernel_launch(void* const* d_in, const int* in_sizes, int n_in,
                              void* d_out, int out_size, void* d_ws, size_t ws_size,
                              hipStream_t stream)
{
    const int*   occ  = (const int*)  d_in[0];
    const float* Sz   = (const float*)d_in[2];
    const float* X    = (const float*)d_in[3];
    const float* Y    = (const float*)d_in[4];
    const float* hv   = (const float*)d_in[5];
    const float* sv   = (const float*)d_in[6];
    const float* dv   = (const float*)d_in[7];
    const float* Jsp  = (const float*)d_in[8];
    const float* JXel = (const float*)d_in[9];
    const float* JYel = (const float*)d_in[10];
    const float* pXX  = (const float*)d_in[11];
    const float* pXY  = (const float*)d_in[12];
    const float* pYY  = (const float*)d_in[13];
    const float* g    = (const float*)d_in[14];
    const float* fS   = (const float*)d_in[15];
    const float* fd   = (const float*)d_in[16];
    const float* zx   = (const float*)d_in[17];
    const float* zy   = (const float*)d_in[18];
    const float* xr   = (const float*)d_in[19];
    const float* yr   = (const float*)d_in[20];
    const float* hop  = (const float*)d_in[21];
    const float* swm  = (const float*)d_in[22];
    const float* dwm  = (const float*)d_in[23];
    const int*   ivic = (const int*)  d_in[24];
    const float* sb   = (const float*)d_in[25];
    const float* stx  = (const float*)d_in[26];
    const float* sty  = (const float*)d_in[27];
    float* out = (float*)d_out;

    char* ws = (char*)d_ws;
    float*  W    = (float*) (ws + 0);           // 16.78 MB
    float*  v0   = (float*) (ws + 16777216);    // 8 KB
    float*  v1   = (float*) (ws + 16785408);    // 4 KB used
    float*  sig2 = (float*) (ws + 16793600);
    int*    sel  = (int*)   (ws + 16801792);
    float*  Mt   = (float*) (ws + 16805888);    // 4 MB; first ~700KB doubles as barrier/V region during Jacobi
    double* G    = (double*)(ws + 21000192);    // 8 MB fp64 Gram; first 1MB doubles as Sg (fp32) during Jacobi
    double* acc  = (double*)(ws + 29388800);    // 32 doubles
    int*    gctl = (int*)   (ws + 29389056);    // [0]=gconv [1]=streak [2..65]=clean
    int*    bars  = (int*)  Mt;                 // global barrier: 10 x 4KB-spaced words (40KB)
    int*    pbars = bars + 10 * 1024;           // pair arrival counters: 32 x 4KB-spaced (128KB)
    int*    vstat = pbars + 32 * 1024;          // V-publication seq: 32 x 128B-spaced (4KB)
    float*  Vbuf  = (float*)(vstat + 1024);     // 32 pairs x 4096 floats (512KB)
    float*  Sg    = (float*)G;                  // 2 x 32 x 4096 floats, double-buffered

    (void)hipMemsetAsync(acc, 0, 768, stream);              // acc + gctl
    (void)hipMemsetAsync(bars, 0, 44 * 4096, stream);       // bars + pbars + vstat
    (void)hipMemsetAsync(Sg, 0, 2 * 32 * 4096 * 4, stream); // Sg both parity buffers
    build_H<<<NN * NN / 256, 256, 0, stream>>>(hop, swm, dwm, hv, sv, dv, X, Y,
                                               ivic, sb, g, fS, fd, W);
    powv_init<<<8, 256, 0, stream>>>(v0);
    for (int it = 0; it < PITER; ++it) {
        const float* vin = (it & 1) ? v1 : v0;
        float* vout = (it & 1) ? v0 : v1;
        matvec<<<NN, 256, 0, stream>>>(W, vin, vout, acc + 8 + it);
    }
    add_shift<<<8, 256, 0, stream>>>(W, acc);

    // single persistent kernel for all NSWB*63 Jacobi rounds
    jac_fused<<<512, 512, 0, stream>>>(W, Sg, Vbuf, gctl, bars, pbars, vstat);

    colnorms<<<NN, 256, 0, stream>>>(W, sig2);
    select_k<<<8, 256, 0, stream>>>(sig2, sel);
    gather_M<<<4096, 256, 0, stream>>>(W, sig2, sel, occ, Mt);
    gram<<<dim3(64, 64), 256, 0, stream>>>(Mt, G);

    for (int s = 0; s < 16; ++s) {
        int k0 = s * 64;
        chol_panel<<<1, 256, 0, stream>>>(G, k0, acc);
        int nrows = LL - k0 - 64;
        if (nrows > 0) {
            chol_trsm<<<nrows / 32, 256, 0, stream>>>(G, k0);
            chol_syrk<<<dim3(nrows / 64, nrows / 64), 256, 0, stream>>>(G, k0);
        }
    }

    pair_sums<<<4096, 256, 0, stream>>>(Sz, X, Y, Jsp, JXel, JYel, pXX, pXY, pYY,
                                        sb, stx, sty, zx, zy, xr, yr, acc);
    finalize<<<1, 1, 0, stream>>>(acc, out);
}

// Round 11
// 41533.487 us; speedup vs baseline: 1.7759x; 1.5049x over previous
//
#include <hip/hip_runtime.h>
#include <math.h>

#define NN 2048   // 2L
#define LL 1024   // L
#define NSWB 5    // blocked Jacobi sweeps. R9 counters: pair-skips never fire
                  // (FETCH identical at JTAU 1e-8 vs 1e-6) because BdG spectra
                  // have degenerate clusters whose Gram couplings never decay;
                  // sweeps past non-degenerate convergence only rotate within
                  // degenerate subspaces (determinant-neutral, 2nd-order).
                  // 8 sweeps gave absmax 0.0 vs threshold 15.76 -> cut to 5.
#define NROUNDS (NSWB * 63)
#define PITER 10  // power iterations for spectral radius
#define JTAU 1e-6f   // relative off^2 threshold (|apq|_rel < 1e-3 -> identity)
#define STREAK_FULL 2016   // 63 rounds x 32 pairs all-skip = one clean sweep

// gctl layout (ints, zeroed at launch): [0]=gconv [1]=streak [2..65]=clean[64]

typedef float vf4 __attribute__((ext_vector_type(4)));   // asm-friendly reg quad

// ---------------------------------------------------------------------------
__global__ void build_H(const float* __restrict__ hop,  const float* __restrict__ swm,
                        const float* __restrict__ dwm,  const float* __restrict__ hv,
                        const float* __restrict__ sv,   const float* __restrict__ dv,
                        const float* __restrict__ X,    const float* __restrict__ Y,
                        const int*   __restrict__ ivic, const float* __restrict__ sb,
                        const float* __restrict__ gg,   const float* __restrict__ fS,
                        const float* __restrict__ fd,   float* __restrict__ W)
{
    int idx = blockIdx.x * 256 + threadIdx.x;
    int r = idx >> 11, c = idx & (NN - 1);
    float hv0 = hv[0], hv1 = hv[1], sv0 = sv[0], dv0 = dv[0];
    float g0 = gg[0], fS0 = fS[0], fd0 = fd[0];

    float val = 0.f;
    #pragma unroll
    for (int t = 0; t < 2; ++t) {
        int rr = t ? c : r;
        int cc = t ? r : c;
        int e  = rr * NN + cc;
        float v = hv0 * hop[e] - hop[NN*NN + e] + hv1 * hop[2*NN*NN + e]
                + sv0 * swm[e] + dv0 * dwm[e];
        int i = rr & (LL - 1), j = cc & (LL - 1);
        float px = 0.f, py = 0.f;
        float s = sb[i * LL + j];
        int n0 = ivic[i*4+0], n1 = ivic[i*4+1], n2 = ivic[i*4+2], n3 = ivic[i*4+3];
        if (j == n1 || j == n3) px = (X[j] - X[i]) * s;
        if (j == n0 || j == n2) py = (Y[j] - Y[i]) * s;
        float P = px + py, Mm = px - py;
        bool rlo = rr < LL, clo = cc < LL;
        if (rlo && clo)        v += g0 * P;
        else if (!rlo && !clo) v -= g0 * P;
        else                   v += fS0 * P + fd0 * Mm;
        val += 0.5f * v;
    }
    W[idx] = val;
}

// --------------------- power iteration for spectral radius ------------------
__global__ void powv_init(float* v)
{
    int i = blockIdx.x * 256 + threadIdx.x;
    if (i < NN) {
        unsigned h = (unsigned)i * 2654435761u;
        h ^= h >> 13; h *= 2246822519u; h ^= h >> 16;
        v[i] = ((h >> 8) * (1.0f / 16777216.f)) - 0.5f;
    }
}

__global__ void matvec(const float* __restrict__ W, const float* __restrict__ vin,
                       float* __restrict__ vout, double* accslot)
{
    __shared__ float red[256];
    int row = blockIdx.x, tid = threadIdx.x;
    const float* wr = W + (size_t)row * NN;
    float s = 0.f;
    for (int j = tid; j < NN; j += 256) s += wr[j] * vin[j];
    red[tid] = s; __syncthreads();
    for (int off = 128; off; off >>= 1) { if (tid < off) red[tid] += red[tid + off]; __syncthreads(); }
    if (tid == 0) { float y = red[0]; vout[row] = y; atomicAdd(accslot, (double)y * (double)y); }
}

__global__ void add_shift(float* W, const double* acc)
{
    int i = blockIdx.x * 256 + threadIdx.x;
    if (i < NN) {
        double n1 = acc[8 + PITER - 1], n0 = acc[8 + PITER - 2];
        float rho = (float)sqrt(n1 / (n0 > 0.0 ? n0 : 1.0));
        W[(size_t)i * NN + i] += 1.45f * rho;
    }
}

// ------------------- blocked Jacobi: fused persistent kernel ----------------
__device__ __forceinline__ void pair_groups(int pair, int r, int& gp, int& gq)
{
    if (pair == 0) gp = 0;
    else { int t1 = pair - 1 + r; if (t1 >= 63) t1 -= 63; gp = 1 + t1; }
    int t2 = 62 - pair + r; if (t2 >= 63) t2 -= 63; gq = 1 + t2;
}

// Fence-free coherence discipline (proven in v3/v5/v7): all cross-block
// traffic uses IF$-coherent accesses (sc0 sc1 / relaxed agent atomics); NO
// acquire/release fences -> no buffer_wbl2/inv. Ordering is manual: every
// wave drains vmcnt(0) before its block's barrier arrival / flag publish.
__device__ __forceinline__ int  ald(const int* p)
{ return __hip_atomic_load(p, __ATOMIC_RELAXED, __HIP_MEMORY_SCOPE_AGENT); }
__device__ __forceinline__ void ast(int* p, int v)
{ __hip_atomic_store(p, v, __ATOMIC_RELAXED, __HIP_MEMORY_SCOPE_AGENT); }
__device__ __forceinline__ void afst(float* p, float v)
{ __hip_atomic_store(p, v, __ATOMIC_RELAXED, __HIP_MEMORY_SCOPE_AGENT); }
__device__ __forceinline__ void afadd(float* p, float v)
{ (void)__hip_atomic_fetch_add(p, v, __ATOMIC_RELAXED, __HIP_MEMORY_SCOPE_AGENT); }

// IF$-coherent load/store (single-writer data; atomicity not required,
// only coherence + manual ordering). ext_vector_type maps to a VGPR quad.
__device__ __forceinline__ vf4 cld4(const float* p)
{ vf4 d; asm volatile("global_load_dwordx4 %0, %1, off sc0 sc1" : "=v"(d) : "v"(p)); return d; }
__device__ __forceinline__ void cst4(float* p, vf4 v)
{ asm volatile("global_store_dwordx4 %0, %1, off sc0 sc1" :: "v"(p), "v"(v) : "memory"); }
__device__ __forceinline__ void cst1(float* p, float v)
{ asm volatile("global_store_dword %0, %1, off sc0 sc1" :: "v"(p), "v"(v) : "memory"); }
__device__ __forceinline__ void waitvm0()
{ asm volatile("s_waitcnt vmcnt(0)" ::: "memory"); __builtin_amdgcn_sched_barrier(0); }

// global tree barrier, fence-free. Words spaced 4KB apart; XCD-local
// sub-counters. ALL waves drain vmcnt before arrival.
__device__ __forceinline__ void gridbar(int* bars, int phase)
{
    waitvm0();
    __syncthreads();
    if (threadIdx.x == 0) {
        int g = blockIdx.x & 7;
        int old = __hip_atomic_fetch_add(&bars[g * 1024], 1,
                      __ATOMIC_RELAXED, __HIP_MEMORY_SCOPE_AGENT);
        if (old == phase * 64 - 1) {                       // group leader
            int t = __hip_atomic_fetch_add(&bars[8 * 1024], 1,
                        __ATOMIC_RELAXED, __HIP_MEMORY_SCOPE_AGENT);
            if (t == phase * 8 - 1)                        // global last
                ast(&bars[9 * 1024], phase);
        }
        while (ald(&bars[9 * 1024]) < phase)
            __builtin_amdgcn_s_sleep(8);
        asm volatile("" ::: "memory");
    }
    __syncthreads();
}

// One kernel for all NSWB*63 rounds, 512 blocks x 512 threads (2/CU by LDS).
// Per round, block (pair,chunk) = (bid>>4, bid&15); solver chunk = pair>>1
// (guarantees no two solver blocks co-reside on one CU under round-robin
// dispatch: co-residents are (b, b+256), and solver ids 16p+(p>>1) vs
// 16(p+16)+((p+16)>>1) differ by 264, never 256).
//   A: zero next-round Sg slice; stage own 64x128 W tile -> TT; partial
//      Gram; global_atomic_add_f32 into Sg[rr&1][pair]; arrive at pbars.
//   B: SOLVER spins for 16 arrivals, reduces Sg -> S, runs the inner-sweep
//      solve (V in registers), writes Vbuf + publishes vstat = pphase*2+act.
//      NON-SOLVERS poll vstat, then read Vbuf -> Vs. No redundant solve ->
//      one solver per CU, private LDS pipe.
//   C: apply TT x V -> W tile (TT reused from A).
//   [global barrier]; uniform convergence break on gctl[0].
// hint is pair-uniform: gctl group words are written only by the owning
// pair's solver in phase B (vmcnt-drained before the end-of-round gridbar)
// and read at round start after the gridbar -> all 16 chunks agree, so
// pphase stays lockstep across the pair (no protocol divergence).
__global__ __launch_bounds__(512, 4) void jac_fused(float* __restrict__ W,
                                                    float* __restrict__ Sg,
                                                    float* __restrict__ Vbuf,
                                                    int* __restrict__ gctl,
                                                    int* __restrict__ bars,
                                                    int* __restrict__ pbars,
                                                    int* __restrict__ vstat)
{
    __shared__ float TT[64][132];   // A/C: 64-col x 128-row W tile
    __shared__ float S[64][65];     // B(solver): pair Gram
    __shared__ float Vs[64][64];    // B->C: V tile
    __shared__ float csC[32], csS[32];
    __shared__ int   pk[32], qk[32];
    __shared__ int   active;
    __shared__ int   nact[2];

    const int tid    = threadIdx.x;
    const int bid    = blockIdx.x;
    const int gpair  = bid >> 4, chunk = bid & 15;
    const int r0     = chunk * 128;
    const bool issol = (chunk == (gpair >> 1));
    const bool ldr   = (issol && tid == 0);      // single writer for gctl
    int gphase = 0, pphase = 0;

    for (int rr = 0; rr < NROUNDS; ++rr) {
        int r = rr; while (r >= 63) r -= 63;
        int gp, gq; pair_groups(gpair, r, gp, gq);
        int c1 = ald(&gctl[2 + gp]);
        int c2 = ald(&gctl[2 + gq]);
        bool hint = (c1 >= 63 && c2 >= 63);
        if (!hint) ++pphase;                     // lockstep across the pair

        // zero next-round Sg slice (last readers were last round, separated
        // by the end-of-round gridbar)
        {
            float* bufn = Sg + ((size_t)(((rr + 1) & 1) * 32 + gpair)) * 4096 + chunk * 256;
            if (tid < 256) afst(&bufn[tid], 0.f);
        }

        // ---------------- phase A: stage + gram + accumulate ----------------
        if (!hint) {
            {
                int q  = tid & 31, r4 = q << 2;
                int cA = tid >> 5;
                vf4 t0 = cld4(W + (size_t)(gp * 32 + cA     ) * NN + r0 + r4);
                vf4 t1 = cld4(W + (size_t)(gp * 32 + cA + 16) * NN + r0 + r4);
                vf4 t2 = cld4(W + (size_t)(gq * 32 + cA     ) * NN + r0 + r4);
                vf4 t3 = cld4(W + (size_t)(gq * 32 + cA + 16) * NN + r0 + r4);
                waitvm0();
                *(vf4*)&TT[cA     ][r4] = t0;
                *(vf4*)&TT[cA + 16][r4] = t1;
                *(vf4*)&TT[cA + 32][r4] = t2;
                *(vf4*)&TT[cA + 48][r4] = t3;
            }
            __syncthreads();
            int tr = tid & 15, tc = tid >> 4;
            float acc[4][2] = {};
            for (int r4 = 0; r4 < 128; r4 += 4) {
                float a[4][4], b[2][4];
                #pragma unroll
                for (int m = 0; m < 4; ++m) *(float4*)a[m] = *(const float4*)&TT[tr + 16*m][r4];
                #pragma unroll
                for (int n = 0; n < 2; ++n) *(float4*)b[n] = *(const float4*)&TT[tc + 32*n][r4];
                #pragma unroll
                for (int m = 0; m < 4; ++m)
                    #pragma unroll
                    for (int n = 0; n < 2; ++n)
                        #pragma unroll
                        for (int k = 0; k < 4; ++k)
                            acc[m][n] += a[m][k] * b[n][k];
            }
            float* bufc = Sg + ((size_t)((rr & 1) * 32 + gpair)) * 4096;
            #pragma unroll
            for (int m = 0; m < 4; ++m)
                #pragma unroll
                for (int n = 0; n < 2; ++n)
                    afadd(&bufc[(tr + 16*m) * 64 + (tc + 32*n)], acc[m][n]);
            waitvm0();                 // every wave drains its Sg adds
            __syncthreads();
            if (tid == 0)
                (void)__hip_atomic_fetch_add(&pbars[gpair * 1024], 1,
                          __ATOMIC_RELAXED, __HIP_MEMORY_SCOPE_AGENT);
        }

        // ---------------- phase B ----------------
        int do_apply = 0;
        if (hint) {
            if (ldr) {
                ast(&gctl[2 + gp], c1 + 1);
                ast(&gctl[2 + gq], c2 + 1);
                int old = __hip_atomic_fetch_add(&gctl[1], 1,
                              __ATOMIC_RELAXED, __HIP_MEMORY_SCOPE_AGENT);
                if (old + 1 >= STREAK_FULL) ast(&gctl[0], 1);
            }
        } else if (issol) {
            // ---- solver: wait for all 16 Gram contributions ----
            if (tid == 0) {
                while (ald(&pbars[gpair * 1024]) < 16 * pphase)
                    __builtin_amdgcn_s_sleep(4);
                active = 0;
            }
            if (tid < 2) nact[tid] = 0;
            __syncthreads();
            {
                const float* bufc = Sg + ((size_t)((rr & 1) * 32 + gpair)) * 4096;
                vf4 s0 = cld4(bufc + 4 * tid);
                vf4 s1 = cld4(bufc + 4 * (tid + 512));
                waitvm0();
                int i0 = tid >> 4, j0 = (tid & 15) << 2;
                int i1 = (tid + 512) >> 4;
                S[i0][j0] = s0.x; S[i0][j0+1] = s0.y; S[i0][j0+2] = s0.z; S[i0][j0+3] = s0.w;
                S[i1][j0] = s1.x; S[i1][j0+1] = s1.y; S[i1][j0+2] = s1.z; S[i1][j0+3] = s1.w;
            }
            __syncthreads();
            int loc = 0;
            for (int e = tid; e < 4096; e += 512) {
                int i = e >> 6, j = e & 63;
                if (i < j) {
                    float o = S[i][j];
                    if (o * o > JTAU * S[i][i] * S[j][j]) loc = 1;
                }
            }
            if (loc) active = 1;          // benign race: only ever set to 1
            __syncthreads();
            if (!active) {
                if (tid == 0) {
                    ast(&gctl[2 + gp], c1 + 1);
                    ast(&gctl[2 + gq], c2 + 1);
                    int old = __hip_atomic_fetch_add(&gctl[1], 1,
                                  __ATOMIC_RELAXED, __HIP_MEMORY_SCOPE_AGENT);
                    if (old + 1 >= STREAK_FULL) ast(&gctl[0], 1);
                    ast(&vstat[gpair * 32], pphase * 2);     // publish: identity
                }
            } else {
                do_apply = 1;
                if (tid == 0) {
                    ast(&gctl[2 + gp], 0);
                    ast(&gctl[2 + gq], 0);
                    __hip_atomic_exchange(&gctl[1], 0,
                        __ATOMIC_RELAXED, __HIP_MEMORY_SCOPE_AGENT);
                }
                int lane = tid & 63, wv = tid >> 6;   // 8 waves; wave w owns V rows 8w..8w+7
                float v[8];
                #pragma unroll
                for (int i = 0; i < 8; ++i) v[i] = (8 * wv + i == lane) ? 1.f : 0.f;

                for (int r2 = 0; r2 < 63; ++r2) {
                    if (tid < 32) {
                        int k = tid, p, q;
                        if (k == 0) p = 0;
                        else { int t1 = k - 1 + r2; if (t1 >= 63) t1 -= 63; p = 1 + t1; }
                        int t2 = 62 - k + r2; if (t2 >= 63) t2 -= 63; q = 1 + t2;
                        float app = S[p][p], aqq = S[q][q], apq = S[p][q];
                        float c = 1.f, s = 0.f;
                        if (apq * apq > JTAU * app * aqq) {
                            // fast-math chain (~1e-7 rel; Jacobi self-corrects)
                            float tau = (aqq - app) * __builtin_amdgcn_rcpf(2.f * apq);
                            float sq  = __builtin_amdgcn_sqrtf(fmaf(tau, tau, 1.f));
                            float t   = (tau >= 0.f ? 1.f : -1.f) *
                                        __builtin_amdgcn_rcpf(fabsf(tau) + sq);
                            c = __builtin_amdgcn_rsqf(fmaf(t, t, 1.f));
                            s = t * c;
                            nact[r2 & 1] = 1;     // benign multi-writer, same value
                        }
                        csC[k] = c; csS[k] = s; pk[k] = p; qk[k] = q;
                    }
                    if (tid == 256) nact[(r2 + 1) & 1] = 0;
                    __syncthreads();
                    if (!nact[r2 & 1]) break;
                    // one-pass S <- J^T S J over disjoint 2x2 blocks (2/thread)
                    for (int u = tid; u < 1024; u += 512) {
                        int ki = u >> 5, kj = u & 31;
                        float si_ = csS[ki], sj_ = csS[kj];
                        if (si_ == 0.f && sj_ == 0.f) continue;
                        float ci_ = csC[ki], cj_ = csC[kj];
                        int pi = pk[ki], qi = qk[ki], pj = pk[kj], qj = qk[kj];
                        float a  = S[pi][pj], b  = S[pi][qj];
                        float c2 = S[qi][pj], d  = S[qi][qj];
                        float a1 = cj_ * a  - sj_ * b,  b1 = sj_ * a  + cj_ * b;
                        float c1 = cj_ * c2 - sj_ * d,  d1 = sj_ * c2 + cj_ * d;
                        S[pi][pj] = ci_ * a1 - si_ * c1;
                        S[qi][pj] = si_ * a1 + ci_ * c1;
                        S[pi][qj] = ci_ * b1 - si_ * d1;
                        S[qi][qj] = si_ * b1 + ci_ * d1;
                    }
                    // V <- V * J (register resident: lane = column, shfl p<->q)
                    {
                        int k;
                        if (lane == 0) k = 0;
                        else { int t = lane - 1 - r2; if (t < 0) t += 63;
                               k = (t <= 30) ? (t + 1) : (62 - t); }
                        float s_ = csS[k];
                        if (s_ != 0.f) {
                            float c_ = csC[k];
                            int p = pk[k], q = qk[k];
                            bool isp = (lane == p);
                            int part = isp ? q : p;
                            #pragma unroll
                            for (int i = 0; i < 8; ++i) {
                                float other = __shfl(v[i], part);
                                v[i] = isp ? (c_ * v[i] - s_ * other)
                                           : (s_ * other + c_ * v[i]);
                            }
                        }
                    }
                    __syncthreads();
                }
                // publish V: LDS (own apply) + Vbuf (other 15 chunks)
                float* vb = Vbuf + ((size_t)gpair << 12);
                #pragma unroll
                for (int i = 0; i < 8; ++i) {
                    Vs[8 * wv + i][lane] = v[i];
                    cst1(vb + (8 * wv + i) * 64 + lane, v[i]);
                }
                waitvm0();                 // every wave drains its V stores
                __syncthreads();
                if (tid == 0) ast(&vstat[gpair * 32], pphase * 2 + 1);
            }
        } else {
            // ---- non-solver: poll for V publication ----
            if (tid == 0) {
                int v;
                while ((v = ald(&vstat[gpair * 32])) < pphase * 2)
                    __builtin_amdgcn_s_sleep(4);
                active = v & 1;
                asm volatile("" ::: "memory");
            }
            __syncthreads();
            if (active) {
                do_apply = 1;
                const float* vb = Vbuf + ((size_t)gpair << 12);
                vf4 a0 = cld4(vb + 4 * tid);
                vf4 a1 = cld4(vb + 4 * (tid + 512));
                waitvm0();
                int i0 = tid >> 4, j0 = (tid & 15) << 2;
                int i1 = (tid + 512) >> 4;
                *(vf4*)&Vs[i0][j0] = a0;
                *(vf4*)&Vs[i1][j0] = a1;
                __syncthreads();
            }
        }

        // ---------------- phase C: apply (TT from A, Vs from B) -------------
        if (do_apply) {
            int rt = tid & 31, ct = tid >> 5;
            int rr0 = rt << 2, c20 = ct << 2;
            float acc[4][4] = {};
            for (int c = 0; c < 64; ++c) {
                float a[4], b[4];
                *(float4*)a = *(const float4*)&TT[c][rr0];
                *(float4*)b = *(const float4*)&Vs[c][c20];
                #pragma unroll
                for (int i = 0; i < 4; ++i)
                    #pragma unroll
                    for (int j = 0; j < 4; ++j)
                        acc[i][j] += a[i] * b[j];
            }
            __syncthreads();           // everyone done reading TT
            #pragma unroll
            for (int j = 0; j < 4; ++j)
                #pragma unroll
                for (int i = 0; i < 4; ++i)
                    TT[c20 + j][rr0 + i] = acc[i][j];
            __syncthreads();
            {
                int q  = tid & 31, r4 = q << 2;
                int cA = tid >> 5;
                cst4(W + (size_t)(gp * 32 + cA     ) * NN + r0 + r4, *(const vf4*)&TT[cA     ][r4]);
                cst4(W + (size_t)(gp * 32 + cA + 16) * NN + r0 + r4, *(const vf4*)&TT[cA + 16][r4]);
                cst4(W + (size_t)(gq * 32 + cA     ) * NN + r0 + r4, *(const vf4*)&TT[cA + 32][r4]);
                cst4(W + (size_t)(gq * 32 + cA + 16) * NN + r0 + r4, *(const vf4*)&TT[cA + 48][r4]);
            }
        }
        gridbar(bars, ++gphase);
        if (ald(&gctl[0])) break;
    }
}

// --------------------- norms, selection, gather -----------------------------
__global__ void colnorms(const float* __restrict__ W, float* __restrict__ sig2)
{
    __shared__ float red[256];
    int col = blockIdx.x, tid = threadIdx.x;
    const float* c = W + (size_t)col * NN;
    float s = 0.f;
    for (int e = tid; e < NN; e += 256) s += c[e] * c[e];
    red[tid] = s; __syncthreads();
    for (int off = 128; off; off >>= 1) { if (tid < off) red[tid] += red[tid + off]; __syncthreads(); }
    if (tid == 0) sig2[col] = red[0];
}

__global__ void select_k(const float* __restrict__ sig2, int* __restrict__ sel)
{
    int i = blockIdx.x * 256 + threadIdx.x;
    if (i >= NN) return;
    float di = sig2[i]; int rank = 0;
    for (int j = 0; j < NN; ++j) {
        float dj = sig2[j];
        rank += (dj < di) || (dj == di && j < i);
    }
    if (rank < LL) sel[rank] = i;
}

__global__ void gather_M(const float* __restrict__ W, const float* __restrict__ sig2,
                         const int* __restrict__ sel, const int* __restrict__ occ,
                         float* __restrict__ Mt)
{
    int idx = blockIdx.x * 256 + threadIdx.x;
    int b = idx >> 10, a = idx & (LL - 1);
    int col = sel[b];
    float rn = 1.f / sqrtf(sig2[col]);
    Mt[(size_t)b * LL + a] = W[(size_t)col * NN + occ[a]] * rn;
}

// G = Mt^T * Mt in fp64 (= M M^T)
__global__ void gram(const float* __restrict__ Mt, double* __restrict__ G)
{
    __shared__ float As[32][17], Bs[32][17];
    int t = threadIdx.x;
    int tx = t & 15, ty = t >> 4;
    int a0 = blockIdx.y * 16, c0 = blockIdx.x * 16;
    double s = 0.0;
    for (int kb = 0; kb < LL; kb += 32) {
        for (int u = t; u < 32 * 16; u += 256) {
            int kr = u >> 4, i = u & 15;
            As[kr][i] = Mt[(size_t)(kb + kr) * LL + a0 + i];
            Bs[kr][i] = Mt[(size_t)(kb + kr) * LL + c0 + i];
        }
        __syncthreads();
        #pragma unroll 8
        for (int k2 = 0; k2 < 32; ++k2)
            s += (double)As[k2][ty] * (double)Bs[k2][tx];
        __syncthreads();
    }
    G[(size_t)(a0 + ty) * LL + (c0 + tx)] = s;
}

// --------------------- blocked fp64 Cholesky (panel 64) ---------------------
__global__ void chol_panel(double* __restrict__ G, int k0, double* __restrict__ acc)
{
    __shared__ double Ld[64][65];
    __shared__ double sinv;
    int tid = threadIdx.x;
    for (int u = tid; u < 4096; u += 256)
        Ld[u >> 6][u & 63] = G[(size_t)(k0 + (u >> 6)) * LL + k0 + (u & 63)];
    __syncthreads();
    double lsum = 0.0;
    for (int c = 0; c < 64; ++c) {
        if (tid == 0) {
            double d = Ld[c][c]; d = d > 1e-300 ? d : 1e-300;
            double sd = sqrt(d); lsum += log(sd);
            Ld[c][c] = sd; sinv = 1.0 / sd;
        }
        __syncthreads();
        if (tid < 63 - c) Ld[c + 1 + tid][c] *= sinv;
        __syncthreads();
        for (int u = tid; u < 4096; u += 256) {
            int rr = u >> 6, cc = u & 63;
            if (rr > c && cc > c) Ld[rr][cc] -= Ld[rr][c] * Ld[cc][c];
        }
        __syncthreads();
    }
    for (int u = tid; u < 4096; u += 256)
        G[(size_t)(k0 + (u >> 6)) * LL + k0 + (u & 63)] = Ld[u >> 6][u & 63];
    if (tid == 0) atomicAdd(acc + 1, lsum);
}

__global__ void chol_trsm(double* __restrict__ G, int k0)
{
    __shared__ double L11[64][65];
    __shared__ double Rt[32][65];
    int tid = threadIdx.x;
    int rbase = k0 + 64 + blockIdx.x * 32;
    for (int u = tid; u < 4096; u += 256)
        L11[u >> 6][u & 63] = G[(size_t)(k0 + (u >> 6)) * LL + k0 + (u & 63)];
    for (int u = tid; u < 2048; u += 256)
        Rt[u >> 6][u & 63] = G[(size_t)(rbase + (u >> 6)) * LL + k0 + (u & 63)];
    __syncthreads();
    for (int c = 0; c < 64; ++c) {
        if (tid < 32) Rt[tid][c] *= 1.0 / L11[c][c];
        __syncthreads();
        for (int u = tid; u < 2048; u += 256) {
            int rr = u >> 6, cc = u & 63;
            if (cc > c) Rt[rr][cc] -= Rt[rr][c] * L11[cc][c];
        }
        __syncthreads();
    }
    for (int u = tid; u < 2048; u += 256)
        G[(size_t)(rbase + (u >> 6)) * LL + k0 + (u & 63)] = Rt[u >> 6][u & 63];
}

__global__ void chol_syrk(double* __restrict__ G, int k0)
{
    __shared__ double At[64][32];
    __shared__ double Bt[64][32];
    int tid = threadIdx.x;
    int r0g = k0 + 64 + blockIdx.y * 64;
    int c0g = k0 + 64 + blockIdx.x * 64;
    int i0 = (tid >> 4) << 2, j0 = (tid & 15) << 2;
    double acc[4][4] = {};
    for (int kh = 0; kh < 2; ++kh) {
        for (int u = tid; u < 2048; u += 256) {
            int i = u >> 5, c = u & 31;
            At[i][c] = G[(size_t)(r0g + i) * LL + k0 + kh * 32 + c];
            Bt[i][c] = G[(size_t)(c0g + i) * LL + k0 + kh * 32 + c];
        }
        __syncthreads();
        for (int c = 0; c < 32; ++c) {
            int cr = (c + tid) & 31;
            double a[4], b[4];
            #pragma unroll
            for (int i = 0; i < 4; ++i) a[i] = At[i0 + i][cr];
            #pragma unroll
            for (int j = 0; j < 4; ++j) b[j] = Bt[j0 + j][cr];
            #pragma unroll
            for (int i = 0; i < 4; ++i)
                #pragma unroll
                for (int j = 0; j < 4; ++j)
                    acc[i][j] += a[i] * b[j];
        }
        __syncthreads();
    }
    #pragma unroll
    for (int i = 0; i < 4; ++i)
        #pragma unroll
        for (int j = 0; j < 4; ++j) {
            size_t e = (size_t)(r0g + i0 + i) * LL + c0g + j0 + j;
            G[e] -= acc[i][j];
        }
}

// --------- all O(L^2) circulant quadratic forms + coherent terms ------------
__global__ void pair_sums(const float* __restrict__ Sz,  const float* __restrict__ X,
                          const float* __restrict__ Y,
                          const float* __restrict__ Jsp, const float* __restrict__ JXel,
                          const float* __restrict__ JYel,const float* __restrict__ pXX,
                          const float* __restrict__ pXY, const float* __restrict__ pYY,
                          const float* __restrict__ sb,  const float* __restrict__ stx,
                          const float* __restrict__ sty,
                          const float* __restrict__ zx,  const float* __restrict__ zy,
                          const float* __restrict__ xr,  const float* __restrict__ yr,
                          double* __restrict__ acc)
{
    __shared__ float tS[289], tXe[289], tYe[289], tXX[289], tXY[289], tYY[289];
    __shared__ double red[256];
    int tid = threadIdx.x;
    for (int u = tid; u < 289; u += 256) {
        tS[u]  = (u < 288) ? Jsp[u] : 0.f;
        tXX[u] = (u < 288) ? pXX[u] : 0.f;
        tXY[u] = (u < 288) ? pXY[u] : 0.f;
        tYY[u] = (u < 288) ? pYY[u] : 0.f;
        tXe[u] = (u >= 1 && u < 288) ? JXel[u - 1] : 0.f;
        tYe[u] = (u >= 1 && u < 288) ? JYel[u - 1] : 0.f;
    }
    __syncthreads();
    int idx = blockIdx.x * 256 + tid;
    int i = idx >> 10, j = idx & (LL - 1);
    int xi = i >> 5, yi = i & 31, xj = j >> 5, yj = j & 31;
    int dx = (xj - xi) & 31, dy = (yj - yi) & 31;
    int rx = (dx <= 16) ? dx : 32 - dx;
    int ry = (dy <= 16) ? dy : 32 - dy;
    int ti = rx * 17 + ry;
    float si = Sz[i], sj = Sz[j];
    float Xi = X[i], Xj = X[j], Yi = Y[i], Yj = Y[j];
    float sbij = sb[i * LL + j];
    double sum = (double)(si * sj) * (double)tS[ti];
    sum += (double)(Xi * Xj) * (double)tXX[ti];
    sum += (double)(Yi * Xj + Xi * Yj) * (double)tXY[ti];
    sum += (double)(Yi * Yj) * (double)tYY[ti];
    sum += (double)(si * sj * sbij) *
           ((double)tXe[ti] * (double)(Xi - Xj) + (double)tYe[ti] * (double)(Yi - Yj));
    if (i == j) {
        float ex = Xi - zx[0] * stx[i];
        float ey = Yi - zy[0] * sty[i];
        sum -= 0.5 * (double)xr[0] * ex * ex + 0.5 * (double)yr[0] * ey * ey;
    }
    red[tid] = sum; __syncthreads();
    for (int off = 128; off; off >>= 1) { if (tid < off) red[tid] += red[tid + off]; __syncthreads(); }
    if (tid == 0) atomicAdd(&acc[0], red[0]);
}

__global__ void finalize(const double* __restrict__ acc, float* __restrict__ out)
{
    out[0] = (float)(acc[0] + acc[1]);
}

// ---------------------------------------------------------------------------
extern "C" void kernel_launch(void* const* d_in, const int* in_sizes, int n_in,
                              void* d_out, int out_size, void* d_ws, size_t ws_size,
                              hipStream_t stream)
{
    const int*   occ  = (const int*)  d_in[0];
    const float* Sz   = (const float*)d_in[2];
    const float* X    = (const float*)d_in[3];
    const float* Y    = (const float*)d_in[4];
    const float* hv   = (const float*)d_in[5];
    const float* sv   = (const float*)d_in[6];
    const float* dv   = (const float*)d_in[7];
    const float* Jsp  = (const float*)d_in[8];
    const float* JXel = (const float*)d_in[9];
    const float* JYel = (const float*)d_in[10];
    const float* pXX  = (const float*)d_in[11];
    const float* pXY  = (const float*)d_in[12];
    const float* pYY  = (const float*)d_in[13];
    const float* g    = (const float*)d_in[14];
    const float* fS   = (const float*)d_in[15];
    const float* fd   = (const float*)d_in[16];
    const float* zx   = (const float*)d_in[17];
    const float* zy   = (const float*)d_in[18];
    const float* xr   = (const float*)d_in[19];
    const float* yr   = (const float*)d_in[20];
    const float* hop  = (const float*)d_in[21];
    const float* swm  = (const float*)d_in[22];
    const float* dwm  = (const float*)d_in[23];
    const int*   ivic = (const int*)  d_in[24];
    const float* sb   = (const float*)d_in[25];
    const float* stx  = (const float*)d_in[26];
    const float* sty  = (const float*)d_in[27];
    float* out = (float*)d_out;

    char* ws = (char*)d_ws;
    float*  W    = (float*) (ws + 0);           // 16.78 MB
    float*  v0   = (float*) (ws + 16777216);    // 8 KB
    float*  v1   = (float*) (ws + 16785408);    // 4 KB used
    float*  sig2 = (float*) (ws + 16793600);
    int*    sel  = (int*)   (ws + 16801792);
    float*  Mt   = (float*) (ws + 16805888);    // 4 MB; first ~700KB doubles as barrier/V region during Jacobi
    double* G    = (double*)(ws + 21000192);    // 8 MB fp64 Gram; first 1MB doubles as Sg (fp32) during Jacobi
    double* acc  = (double*)(ws + 29388800);    // 32 doubles
    int*    gctl = (int*)   (ws + 29389056);    // [0]=gconv [1]=streak [2..65]=clean
    int*    bars  = (int*)  Mt;                 // global barrier: 10 x 4KB-spaced words (40KB)
    int*    pbars = bars + 10 * 1024;           // pair arrival counters: 32 x 4KB-spaced (128KB)
    int*    vstat = pbars + 32 * 1024;          // V-publication seq: 32 x 128B-spaced (4KB)
    float*  Vbuf  = (float*)(vstat + 1024);     // 32 pairs x 4096 floats (512KB)
    float*  Sg    = (float*)G;                  // 2 x 32 x 4096 floats, double-buffered

    (void)hipMemsetAsync(acc, 0, 768, stream);              // acc + gctl
    (void)hipMemsetAsync(bars, 0, 44 * 4096, stream);       // bars + pbars + vstat
    (void)hipMemsetAsync(Sg, 0, 2 * 32 * 4096 * 4, stream); // Sg both parity buffers
    build_H<<<NN * NN / 256, 256, 0, stream>>>(hop, swm, dwm, hv, sv, dv, X, Y,
                                               ivic, sb, g, fS, fd, W);
    powv_init<<<8, 256, 0, stream>>>(v0);
    for (int it = 0; it < PITER; ++it) {
        const float* vin = (it & 1) ? v1 : v0;
        float* vout = (it & 1) ? v0 : v1;
        matvec<<<NN, 256, 0, stream>>>(W, vin, vout, acc + 8 + it);
    }
    add_shift<<<8, 256, 0, stream>>>(W, acc);

    // single persistent kernel for all NSWB*63 Jacobi rounds
    jac_fused<<<512, 512, 0, stream>>>(W, Sg, Vbuf, gctl, bars, pbars, vstat);

    colnorms<<<NN, 256, 0, stream>>>(W, sig2);
    select_k<<<8, 256, 0, stream>>>(sig2, sel);
    gather_M<<<4096, 256, 0, stream>>>(W, sig2, sel, occ, Mt);
    gram<<<dim3(64, 64), 256, 0, stream>>>(Mt, G);

    for (int s = 0; s < 16; ++s) {
        int k0 = s * 64;
        chol_panel<<<1, 256, 0, stream>>>(G, k0, acc);
        int nrows = LL - k0 - 64;
        if (nrows > 0) {
            chol_trsm<<<nrows / 32, 256, 0, stream>>>(G, k0);
            chol_syrk<<<dim3(nrows / 64, nrows / 64), 256, 0, stream>>>(G, k0);
        }
    }

    pair_sums<<<4096, 256, 0, stream>>>(Sz, X, Y, Jsp, JXel, JYel, pXX, pXY, pYY,
                                        sb, stx, sty, zx, zy, xr, yr, acc);
    finalize<<<1, 1, 0, stream>>>(acc, out);
}